// Round 1
// baseline (1168.289 us; speedup 1.0000x reference)
//
#include <hip/hip_runtime.h>
#include <math.h>

// Problem constants (B=4, S=2048, D=1024, R=128, N=64, K=8)
#define T_TOK 8192
#define DDIM  1024
#define RDIM  128
#define NEXP  64
#define TOPK  8

// d_out layout (floats), reference return order: output, weights, topk_idx, scores
#define OUT_O_OFF 0
#define OUT_W_OFF (T_TOK * RDIM)                 // 1048576
#define OUT_I_OFF (OUT_W_OFF + T_TOK * TOPK)     // 1114112
#define OUT_S_OFF (OUT_I_OFF + T_TOK * TOPK)     // 1179648

// ws layout (bytes)
//   0      counts  int[64]
//   256    fill    int[64]
//   512    offsets int[64]
//   1024   list_tok int[65536]
//   263168 list_w   float[65536]

// ---------------------------------------------------------------------------
// Kernel 1: router scores (fp64 accumulate), top-8, softmax, expert counts.
// One wave (64 lanes) per token; lane n owns expert n.
// ---------------------------------------------------------------------------
__global__ __launch_bounds__(64) void router_kernel(
    const float* __restrict__ x, const float* __restrict__ rw,
    float* __restrict__ out, int* __restrict__ counts)
{
  const int token = blockIdx.x;
  const int lane  = threadIdx.x;

  __shared__ float xs[DDIM];
  const float4* xr = reinterpret_cast<const float4*>(x + (size_t)token * DDIM);
  float4* xsv = reinterpret_cast<float4*>(xs);
#pragma unroll
  for (int i = 0; i < DDIM / 4 / 64; ++i) xsv[lane + 64 * i] = xr[lane + 64 * i];
  __syncthreads();

  const float* w = rw + (size_t)lane * DDIM;
  double acc = 0.0;
#pragma unroll 4
  for (int d = 0; d < DDIM; d += 4) {
    float4 wv = *reinterpret_cast<const float4*>(w + d);
    acc += (double)xs[d + 0] * (double)wv.x;
    acc += (double)xs[d + 1] * (double)wv.y;
    acc += (double)xs[d + 2] * (double)wv.z;
    acc += (double)xs[d + 3] * (double)wv.w;
  }
  const float v = (float)acc;
  out[OUT_S_OFF + token * NEXP + lane] = v;

  // top-8 via repeated wave argmax (tie-break: lowest index, matches lax.top_k)
  float cur = v;
  float topv[TOPK];
  int   topi[TOPK];
  for (int k = 0; k < TOPK; ++k) {
    float bv = cur;
    int   bi = lane;
#pragma unroll
    for (int off = 32; off >= 1; off >>= 1) {
      float ov = __shfl_xor(bv, off);
      int   oi = __shfl_xor(bi, off);
      if (ov > bv || (ov == bv && oi < bi)) { bv = ov; bi = oi; }
    }
    topv[k] = bv;
    topi[k] = bi;
    if (lane == bi) cur = -INFINITY;
  }

  // softmax over the 8 maxima (redundant in all lanes; trivial cost)
  const float m = topv[0];
  float wk[TOPK];
  float s = 0.f;
#pragma unroll
  for (int k = 0; k < TOPK; ++k) { wk[k] = expf(topv[k] - m); s += wk[k]; }
  const float inv = 1.f / s;

  if (lane < TOPK) {
    out[OUT_W_OFF + token * TOPK + lane] = wk[lane] * inv;
    out[OUT_I_OFF + token * TOPK + lane] = (float)topi[lane];  // idx as float value
    atomicAdd(&counts[topi[lane]], 1);
  }
}

// ---------------------------------------------------------------------------
// Kernel 2: exclusive prefix sum over 64 expert counts (trivial).
// ---------------------------------------------------------------------------
__global__ void scan_kernel(const int* __restrict__ counts, int* __restrict__ offsets)
{
  if (threadIdx.x == 0) {
    int acc = 0;
    for (int n = 0; n < NEXP; ++n) { offsets[n] = acc; acc += counts[n]; }
  }
}

// ---------------------------------------------------------------------------
// Kernel 3: scatter (token, weight) into per-expert compacted lists.
// ---------------------------------------------------------------------------
__global__ __launch_bounds__(256) void scatter_kernel(
    const float* __restrict__ out, const int* __restrict__ offsets,
    int* __restrict__ fill, int* __restrict__ list_tok, float* __restrict__ list_w)
{
  const int e = blockIdx.x * 256 + threadIdx.x;  // 0 .. 65535
  const int token = e >> 3;
  const int n = (int)out[OUT_I_OFF + e];
  const float w = out[OUT_W_OFF + e];
  const int pos = atomicAdd(&fill[n], 1);
  const int slot = offsets[n] + pos;
  list_tok[slot] = token;
  list_w[slot]  = w;
}

// ---------------------------------------------------------------------------
// Kernel 4: per-expert tiled GEMM.  Block = (expert, 64-token tile).
// 256 threads: thread = (tg = t&31 -> 2 token rows, rc = t>>5 -> 16 R cols).
// LDS-staged x tile [64][33] (padded) and C chunk [32][128].
// Epilogue: out[tok, r] += weight * acc  via f32 atomics (8 experts/token).
// ---------------------------------------------------------------------------
#define TT 64
#define DC 32

__global__ __launch_bounds__(256) void gemm_kernel(
    const float* __restrict__ x, const float* __restrict__ cn,
    const int* __restrict__ counts, const int* __restrict__ offsets,
    const int* __restrict__ list_tok, const float* __restrict__ list_w,
    float* __restrict__ out)
{
  const int n = blockIdx.x;
  const int cnt = counts[n];
  const int start = blockIdx.y * TT;
  if (start >= cnt) return;
  const int nrows = min(TT, cnt - start);
  const int base = offsets[n] + start;

  __shared__ float xs[TT][DC + 1];   // 64 x 33 floats (pad -> 2-way max on reads)
  __shared__ float cs[DC][RDIM];     // 32 x 128 floats

  const int t  = threadIdx.x;
  const int tg = t & 31;
  const int rc = t >> 5;             // 0..7  (columns rc*16 .. rc*16+15)
  const int row0 = tg * 2;
  const int row1 = tg * 2 + 1;

  // staging rows for this thread: rA = t>>3, rB = rA + 32
  const int rA = t >> 3;
  const int rB = rA + 32;
  const int jA = t & 7;
  const int tokA = (rA < nrows) ? list_tok[base + rA] : -1;
  const int tokB = (rB < nrows) ? list_tok[base + rB] : -1;

  float acc0[16], acc1[16];
#pragma unroll
  for (int j = 0; j < 16; ++j) { acc0[j] = 0.f; acc1[j] = 0.f; }

  const float* cbase = cn + (size_t)n * DDIM * RDIM;

  for (int dc = 0; dc < DDIM; dc += DC) {
    // stage x: 64 rows x 32 floats (gathered rows, coalesced 8xfloat4 per row)
    {
      float4 v = make_float4(0.f, 0.f, 0.f, 0.f);
      if (tokA >= 0)
        v = *reinterpret_cast<const float4*>(x + (size_t)tokA * DDIM + dc + jA * 4);
      xs[rA][jA * 4 + 0] = v.x; xs[rA][jA * 4 + 1] = v.y;
      xs[rA][jA * 4 + 2] = v.z; xs[rA][jA * 4 + 3] = v.w;
      float4 u = make_float4(0.f, 0.f, 0.f, 0.f);
      if (tokB >= 0)
        u = *reinterpret_cast<const float4*>(x + (size_t)tokB * DDIM + dc + jA * 4);
      xs[rB][jA * 4 + 0] = u.x; xs[rB][jA * 4 + 1] = u.y;
      xs[rB][jA * 4 + 2] = u.z; xs[rB][jA * 4 + 3] = u.w;
    }
    // stage C chunk: 32 x 128 floats = 1024 float4, 4 per thread, coalesced
#pragma unroll
    for (int p = 0; p < 4; ++p) {
      const int f  = t + p * 256;      // 0..1023
      const int dr = f >> 5;           // 0..31
      const int c4 = f & 31;           // col/4
      float4 v = *reinterpret_cast<const float4*>(cbase + (size_t)(dc + dr) * RDIM + c4 * 4);
      *reinterpret_cast<float4*>(&cs[dr][c4 * 4]) = v;
    }
    __syncthreads();

#pragma unroll 4
    for (int d = 0; d < DC; ++d) {
      const float x0 = xs[row0][d];
      const float x1 = xs[row1][d];
      const float4* cp = reinterpret_cast<const float4*>(&cs[d][rc * 16]);
      float cv[16];
      *reinterpret_cast<float4*>(&cv[0])  = cp[0];
      *reinterpret_cast<float4*>(&cv[4])  = cp[1];
      *reinterpret_cast<float4*>(&cv[8])  = cp[2];
      *reinterpret_cast<float4*>(&cv[12]) = cp[3];
#pragma unroll
      for (int j = 0; j < 16; ++j) {
        acc0[j] += x0 * cv[j];
        acc1[j] += x1 * cv[j];
      }
    }
    __syncthreads();
  }

  // epilogue: out[tok, :] += weight * proj   (f32 atomic accumulation)
  if (row0 < nrows) {
    const int tok  = list_tok[base + row0];
    const float wg = list_w[base + row0];
    float* orow = out + OUT_O_OFF + (size_t)tok * RDIM + rc * 16;
#pragma unroll
    for (int j = 0; j < 16; ++j) unsafeAtomicAdd(&orow[j], acc0[j] * wg);
  }
  if (row1 < nrows) {
    const int tok  = list_tok[base + row1];
    const float wg = list_w[base + row1];
    float* orow = out + OUT_O_OFF + (size_t)tok * RDIM + rc * 16;
#pragma unroll
    for (int j = 0; j < 16; ++j) unsafeAtomicAdd(&orow[j], acc1[j] * wg);
  }
}

// ---------------------------------------------------------------------------
extern "C" void kernel_launch(void* const* d_in, const int* in_sizes, int n_in,
                              void* d_out, int out_size, void* d_ws, size_t ws_size,
                              hipStream_t stream)
{
  (void)in_sizes; (void)n_in; (void)out_size; (void)ws_size;

  const float* x  = (const float*)d_in[0];
  const float* rw = (const float*)d_in[1];
  const float* cn = (const float*)d_in[2];
  float* out = (float*)d_out;

  char* ws = (char*)d_ws;
  int*   counts   = (int*)(ws);
  int*   fill     = (int*)(ws + 256);
  int*   offsets  = (int*)(ws + 512);
  int*   list_tok = (int*)(ws + 1024);
  float* list_w   = (float*)(ws + 1024 + T_TOK * TOPK * sizeof(int));

  // zero counts+fill, zero the accumulated output region
  hipMemsetAsync(ws, 0, 1024, stream);
  hipMemsetAsync(d_out, 0, (size_t)T_TOK * RDIM * sizeof(float), stream);

  router_kernel<<<T_TOK, 64, 0, stream>>>(x, rw, out, counts);
  scan_kernel<<<1, 64, 0, stream>>>(counts, offsets);
  scatter_kernel<<<T_TOK * TOPK / 256, 256, 0, stream>>>(out, offsets, fill, list_tok, list_w);

  dim3 grid(NEXP, (T_TOK * TOPK) / TT);  // 64 x 1024, inactive tiles early-exit
  gemm_kernel<<<grid, 256, 0, stream>>>(x, cn, counts, offsets, list_tok, list_w, out);
}

// Round 2
// 363.226 us; speedup vs baseline: 3.2164x; 3.2164x over previous
//
#include <hip/hip_runtime.h>
#include <math.h>

typedef unsigned int  u32;
typedef unsigned short u16;

// Problem constants (B=4, S=2048, D=1024, R=128, N=64, K=8)
#define T_TOK 8192
#define DDIM  1024
#define RDIM  128
#define NEXP  64
#define TOPK  8

// d_out layout (floats), reference return order: output, weights, topk_idx, scores
#define OUT_O_OFF 0
#define OUT_W_OFF (T_TOK * RDIM)                 // 1048576
#define OUT_I_OFF (OUT_W_OFF + T_TOK * TOPK)     // 1114112
#define OUT_S_OFF (OUT_I_OFF + T_TOK * TOPK)     // 1179648

// ws layout (bytes)
//   0        counts   int[64]
//   256      fill     int[64]
//   512      offsets  int[64]
//   1024     list_tk  int[65536]   (entry = token*8 + kpos)
//   263168   list_w   float[65536]
//   525312   x_bf     u16[8192*1024]        (16 MB)
//   +16M     cn_bt    u16[64*128*1024]      (16 MB, [n][r][d])
//   +32M     proj_bf  u16[65536*128]        (16 MB, slot = token*8+k)

typedef __attribute__((ext_vector_type(8))) short bf16x8;
typedef __attribute__((ext_vector_type(4))) float f32x4;

__device__ __forceinline__ u16 f2bf(float f) {
  union { float f; u32 u; } v; v.f = f;
  u32 r = v.u + 0x7fffu + ((v.u >> 16) & 1u);   // RNE
  return (u16)(r >> 16);
}
__device__ __forceinline__ float bf2f(u16 h) {
  union { u32 u; float f; } v; v.u = ((u32)h) << 16;
  return v.f;
}

// ---------------------------------------------------------------------------
// convert x fp32 -> bf16 (8 elems/thread)
// ---------------------------------------------------------------------------
__global__ __launch_bounds__(256) void convert_x_kernel(
    const float* __restrict__ x, u16* __restrict__ xbf)
{
  const int i = blockIdx.x * 256 + threadIdx.x;   // 0 .. 1048575
  const float4 a = reinterpret_cast<const float4*>(x)[i * 2];
  const float4 b = reinterpret_cast<const float4*>(x)[i * 2 + 1];
  uint4 o;
  o.x = (u32)f2bf(a.x) | ((u32)f2bf(a.y) << 16);
  o.y = (u32)f2bf(a.z) | ((u32)f2bf(a.w) << 16);
  o.z = (u32)f2bf(b.x) | ((u32)f2bf(b.y) << 16);
  o.w = (u32)f2bf(b.z) | ((u32)f2bf(b.w) << 16);
  reinterpret_cast<uint4*>(xbf)[i] = o;
}

// ---------------------------------------------------------------------------
// transpose+convert cn [n][d][r] fp32 -> cn_bt [n][r][d] bf16, 32x32 tiles
// grid (64, 32 d-tiles, 4 r-tiles), block 256
// ---------------------------------------------------------------------------
__global__ __launch_bounds__(256) void convert_cn_kernel(
    const float* __restrict__ cn, u16* __restrict__ cnbt)
{
  const int n  = blockIdx.x;
  const int d0 = blockIdx.y * 32;
  const int r0 = blockIdx.z * 32;
  __shared__ float ts[32][33];
  const int t = threadIdx.x;
  {
    const int dr = t >> 3, rq = t & 7;
    float4 v = *reinterpret_cast<const float4*>(
        cn + ((size_t)n * DDIM + d0 + dr) * RDIM + r0 + rq * 4);
    ts[dr][rq * 4 + 0] = v.x; ts[dr][rq * 4 + 1] = v.y;
    ts[dr][rq * 4 + 2] = v.z; ts[dr][rq * 4 + 3] = v.w;
  }
  __syncthreads();
  {
    const int rr = t >> 3, dq = t & 7;
    ushort4 o;
    o.x = f2bf(ts[dq * 4 + 0][rr]);
    o.y = f2bf(ts[dq * 4 + 1][rr]);
    o.z = f2bf(ts[dq * 4 + 2][rr]);
    o.w = f2bf(ts[dq * 4 + 3][rr]);
    *reinterpret_cast<ushort4*>(
        cnbt + ((size_t)n * RDIM + r0 + rr) * DDIM + d0 + dq * 4) = o;
  }
}

// ---------------------------------------------------------------------------
// Router GEMM: scores = x @ rw^T, fp64 accumulate in ascending-d order
// (bit-identical to the round-1 passing router). Block = 32 tokens x 64 exp.
// Thread (ti=t&15, ei=t>>4): 2 tokens x 4 experts.
// ---------------------------------------------------------------------------
__global__ __launch_bounds__(256) void router_gemm_kernel(
    const float* __restrict__ x, const float* __restrict__ rw,
    float* __restrict__ out)
{
  const int tok0 = blockIdx.x * 32;
  const int t  = threadIdx.x;
  const int ti = t & 15;
  const int ei = t >> 4;
  const int ti2 = ti * 2;
  const int e4  = ei * 4;

  __shared__ float xs[32][68];
  __shared__ float wsm[64][68];

  double acc[2][4];
#pragma unroll
  for (int a = 0; a < 2; ++a)
#pragma unroll
    for (int b = 0; b < 4; ++b) acc[a][b] = 0.0;

  for (int dc = 0; dc < DDIM; dc += 64) {
    // stage x: 32 rows x 16 float4 = 512; 2 per thread
#pragma unroll
    for (int p = 0; p < 2; ++p) {
      const int idx = t + p * 256;
      const int row = idx >> 4, q = idx & 15;
      float4 v = *reinterpret_cast<const float4*>(
          x + (size_t)(tok0 + row) * DDIM + dc + q * 4);
      *reinterpret_cast<float4*>(&xs[row][q * 4]) = v;
    }
    // stage rw: 64 rows x 16 float4 = 1024; 4 per thread
#pragma unroll
    for (int p = 0; p < 4; ++p) {
      const int idx = t + p * 256;
      const int row = idx >> 4, q = idx & 15;
      float4 v = *reinterpret_cast<const float4*>(
          rw + (size_t)row * DDIM + dc + q * 4);
      *reinterpret_cast<float4*>(&wsm[row][q * 4]) = v;
    }
    __syncthreads();

#pragma unroll 2
    for (int d4 = 0; d4 < 64; d4 += 4) {
      float4 xv0 = *reinterpret_cast<const float4*>(&xs[ti2][d4]);
      float4 xv1 = *reinterpret_cast<const float4*>(&xs[ti2 + 1][d4]);
      float4 wv0 = *reinterpret_cast<const float4*>(&wsm[e4 + 0][d4]);
      float4 wv1 = *reinterpret_cast<const float4*>(&wsm[e4 + 1][d4]);
      float4 wv2 = *reinterpret_cast<const float4*>(&wsm[e4 + 2][d4]);
      float4 wv3 = *reinterpret_cast<const float4*>(&wsm[e4 + 3][d4]);
      // ascending-d accumulation per output
      acc[0][0] += (double)xv0.x * (double)wv0.x; acc[0][0] += (double)xv0.y * (double)wv0.y;
      acc[0][0] += (double)xv0.z * (double)wv0.z; acc[0][0] += (double)xv0.w * (double)wv0.w;
      acc[0][1] += (double)xv0.x * (double)wv1.x; acc[0][1] += (double)xv0.y * (double)wv1.y;
      acc[0][1] += (double)xv0.z * (double)wv1.z; acc[0][1] += (double)xv0.w * (double)wv1.w;
      acc[0][2] += (double)xv0.x * (double)wv2.x; acc[0][2] += (double)xv0.y * (double)wv2.y;
      acc[0][2] += (double)xv0.z * (double)wv2.z; acc[0][2] += (double)xv0.w * (double)wv2.w;
      acc[0][3] += (double)xv0.x * (double)wv3.x; acc[0][3] += (double)xv0.y * (double)wv3.y;
      acc[0][3] += (double)xv0.z * (double)wv3.z; acc[0][3] += (double)xv0.w * (double)wv3.w;
      acc[1][0] += (double)xv1.x * (double)wv0.x; acc[1][0] += (double)xv1.y * (double)wv0.y;
      acc[1][0] += (double)xv1.z * (double)wv0.z; acc[1][0] += (double)xv1.w * (double)wv0.w;
      acc[1][1] += (double)xv1.x * (double)wv1.x; acc[1][1] += (double)xv1.y * (double)wv1.y;
      acc[1][1] += (double)xv1.z * (double)wv1.z; acc[1][1] += (double)xv1.w * (double)wv1.w;
      acc[1][2] += (double)xv1.x * (double)wv2.x; acc[1][2] += (double)xv1.y * (double)wv2.y;
      acc[1][2] += (double)xv1.z * (double)wv2.z; acc[1][2] += (double)xv1.w * (double)wv2.w;
      acc[1][3] += (double)xv1.x * (double)wv3.x; acc[1][3] += (double)xv1.y * (double)wv3.y;
      acc[1][3] += (double)xv1.z * (double)wv3.z; acc[1][3] += (double)xv1.w * (double)wv3.w;
    }
    __syncthreads();
  }

#pragma unroll
  for (int a = 0; a < 2; ++a) {
    float4 o;
    o.x = (float)acc[a][0]; o.y = (float)acc[a][1];
    o.z = (float)acc[a][2]; o.w = (float)acc[a][3];
    *reinterpret_cast<float4*>(
        out + OUT_S_OFF + (size_t)(tok0 + ti2 + a) * NEXP + e4) = o;
  }
}

// ---------------------------------------------------------------------------
// Top-8 + softmax + expert counts. 4 tokens per 256-thread block (wave each).
// ---------------------------------------------------------------------------
__global__ __launch_bounds__(256) void topk_kernel(
    float* __restrict__ out, int* __restrict__ counts)
{
  const int token = blockIdx.x * 4 + (threadIdx.x >> 6);
  const int lane  = threadIdx.x & 63;

  const float v = out[OUT_S_OFF + (size_t)token * NEXP + lane];
  float cur = v;
  float topv[TOPK];
  int   topi[TOPK];
  for (int k = 0; k < TOPK; ++k) {
    float bv = cur;
    int   bi = lane;
#pragma unroll
    for (int off = 32; off >= 1; off >>= 1) {
      float ov = __shfl_xor(bv, off);
      int   oi = __shfl_xor(bi, off);
      if (ov > bv || (ov == bv && oi < bi)) { bv = ov; bi = oi; }
    }
    topv[k] = bv;
    topi[k] = bi;
    if (lane == bi) cur = -INFINITY;
  }
  const float m = topv[0];
  float wk[TOPK];
  float s = 0.f;
#pragma unroll
  for (int k = 0; k < TOPK; ++k) { wk[k] = expf(topv[k] - m); s += wk[k]; }
  const float inv = 1.f / s;

  if (lane < TOPK) {
    out[OUT_W_OFF + (size_t)token * TOPK + lane] = wk[lane] * inv;
    out[OUT_I_OFF + (size_t)token * TOPK + lane] = (float)topi[lane];
    atomicAdd(&counts[topi[lane]], 1);
  }
}

// ---------------------------------------------------------------------------
__global__ void scan_kernel(const int* __restrict__ counts, int* __restrict__ offsets)
{
  if (threadIdx.x == 0) {
    int acc = 0;
    for (int n = 0; n < NEXP; ++n) { offsets[n] = acc; acc += counts[n]; }
  }
}

// ---------------------------------------------------------------------------
// Scatter (token*8+k, weight) into per-expert compacted lists.
// ---------------------------------------------------------------------------
__global__ __launch_bounds__(256) void scatter_kernel(
    const float* __restrict__ out, const int* __restrict__ offsets,
    int* __restrict__ fill, int* __restrict__ list_tk, float* __restrict__ list_w)
{
  const int e = blockIdx.x * 256 + threadIdx.x;  // 0..65535 = token*8+k
  const int n = (int)out[OUT_I_OFF + e];
  const float w = out[OUT_W_OFF + e];
  const int pos = atomicAdd(&fill[n], 1);
  const int slot = offsets[n] + pos;
  list_tk[slot] = e;
  list_w[slot]  = w;
}

// ---------------------------------------------------------------------------
// MFMA expert GEMM. Block = (expert n, 64-token tile). 256 thr = 4 waves.
// Wave w: tokens [w*16, w*16+16), all 128 R cols (8 n-frags), K=1024.
// LDS: xs [64 tok][64 k] bf16, bs [128 r][64 k] bf16; 16B pieces XOR-swizzled
// by (row&7) -> frag ds_read_b128 is 2-way max (free).
// MODE 0: store unweighted proj bf16 at slot=token*8+k.  MODE 1: atomic f32.
// ---------------------------------------------------------------------------
template<int MODE>
__global__ __launch_bounds__(256) void mfma_gemm_kernel(
    const u16* __restrict__ xbf, const u16* __restrict__ cnbt,
    const int* __restrict__ counts, const int* __restrict__ offsets,
    const int* __restrict__ list_tk,
    float* __restrict__ out, u16* __restrict__ projbf)
{
  const int n = blockIdx.x;
  const int cnt = counts[n];
  const int start = blockIdx.y * 64;
  if (start >= cnt) return;
  const int nrows = min(64, cnt - start);
  const int base = offsets[n] + start;

  __shared__ __align__(16) u16 xsArr[64 * 64];
  __shared__ __align__(16) u16 bsArr[128 * 64];

  const int t = threadIdx.x;
  const int l = t & 63;
  const int w = t >> 6;
  const int cl = l & 15;
  const int kq = l >> 4;          // 0..3
  const int arow = w * 16 + cl;   // A row this lane reads

  // staging coords (fixed per thread)
  const int rowA = t >> 3;        // 0..31
  const int rowB = rowA + 32;
  const int pA   = t & 7;
  const int tokA = (rowA < nrows) ? (list_tk[base + rowA] >> 3) : -1;
  const int tokB = (rowB < nrows) ? (list_tk[base + rowB] >> 3) : -1;

  f32x4 acc[8];
#pragma unroll
  for (int f = 0; f < 8; ++f) acc[f] = (f32x4){0.f, 0.f, 0.f, 0.f};

  const u16* cnb = cnbt + (size_t)n * RDIM * DDIM;
  const uint4 z4 = make_uint4(0, 0, 0, 0);

  for (int dc = 0; dc < DDIM; dc += 64) {
    // stage A (64 rows x 8 pieces of 16B)
    {
      uint4 v = z4;
      if (tokA >= 0)
        v = *reinterpret_cast<const uint4*>(xbf + (size_t)tokA * DDIM + dc + pA * 8);
      *reinterpret_cast<uint4*>(&xsArr[rowA * 64 + ((pA ^ (rowA & 7)) * 8)]) = v;
      uint4 u = z4;
      if (tokB >= 0)
        u = *reinterpret_cast<const uint4*>(xbf + (size_t)tokB * DDIM + dc + pA * 8);
      *reinterpret_cast<uint4*>(&xsArr[rowB * 64 + ((pA ^ (rowB & 7)) * 8)]) = u;
    }
    // stage B (128 rows x 8 pieces)
#pragma unroll
    for (int p4 = 0; p4 < 4; ++p4) {
      const int r = rowA + p4 * 32;
      uint4 v = *reinterpret_cast<const uint4*>(cnb + (size_t)r * DDIM + dc + pA * 8);
      *reinterpret_cast<uint4*>(&bsArr[r * 64 + ((pA ^ (r & 7)) * 8)]) = v;
    }
    __syncthreads();

#pragma unroll
    for (int ks = 0; ks < 2; ++ks) {
      const int piece = ks * 4 + kq;
      bf16x8 a = *reinterpret_cast<const bf16x8*>(
          &xsArr[arow * 64 + ((piece ^ (arow & 7)) * 8)]);
#pragma unroll
      for (int f = 0; f < 8; ++f) {
        const int r = f * 16 + cl;
        bf16x8 b = *reinterpret_cast<const bf16x8*>(
            &bsArr[r * 64 + ((piece ^ (r & 7)) * 8)]);
        acc[f] = __builtin_amdgcn_mfma_f32_16x16x32_bf16(a, b, acc[f], 0, 0, 0);
      }
    }
    __syncthreads();
  }

  // epilogue: C/D layout row=(l>>4)*4+reg, col = f*16 + (l&15)
#pragma unroll
  for (int j = 0; j < 4; ++j) {
    const int row = w * 16 + kq * 4 + j;
    if (row < nrows) {
      const int tk = list_tk[base + row];
      if (MODE == 0) {
        u16* prow = projbf + (size_t)tk * RDIM + cl;
#pragma unroll
        for (int f = 0; f < 8; ++f) prow[f * 16] = f2bf(acc[f][j]);
      } else {
        const float wg = out[OUT_W_OFF + tk];
        float* orow = out + OUT_O_OFF + (size_t)(tk >> 3) * RDIM + cl;
#pragma unroll
        for (int f = 0; f < 8; ++f) unsafeAtomicAdd(&orow[f * 16], wg * acc[f][j]);
      }
    }
  }
}

// ---------------------------------------------------------------------------
// Combine: out[tok][r] = sum_k w[tok][k] * proj[tok*8+k][r].  Wave per token.
// ---------------------------------------------------------------------------
__global__ __launch_bounds__(256) void combine_kernel(
    const u16* __restrict__ projbf, float* __restrict__ out)
{
  const int token = blockIdx.x * 4 + (threadIdx.x >> 6);
  const int l = threadIdx.x & 63;
  float wts[TOPK];
#pragma unroll
  for (int k = 0; k < TOPK; ++k) wts[k] = out[OUT_W_OFF + (size_t)token * TOPK + k];
  float s0 = 0.f, s1 = 0.f;
#pragma unroll
  for (int k = 0; k < TOPK; ++k) {
    const u32 u = *reinterpret_cast<const u32*>(
        projbf + ((size_t)token * TOPK + k) * RDIM + l * 2);
    s0 += wts[k] * bf2f((u16)(u & 0xffff));
    s1 += wts[k] * bf2f((u16)(u >> 16));
  }
  float2 o; o.x = s0; o.y = s1;
  *reinterpret_cast<float2*>(out + OUT_O_OFF + (size_t)token * RDIM + l * 2) = o;
}

// ---------------------------------------------------------------------------
// Tier-2 fallback: round-1 fp32 gemm (proven), adapted to tk-lists.
// ---------------------------------------------------------------------------
__global__ __launch_bounds__(256) void gemm_f32_kernel(
    const float* __restrict__ x, const float* __restrict__ cn,
    const int* __restrict__ counts, const int* __restrict__ offsets,
    const int* __restrict__ list_tk, const float* __restrict__ list_w,
    float* __restrict__ out)
{
  const int n = blockIdx.x;
  const int cnt = counts[n];
  const int start = blockIdx.y * 64;
  if (start >= cnt) return;
  const int nrows = min(64, cnt - start);
  const int base = offsets[n] + start;

  __shared__ float xs[64][33];
  __shared__ float cs[32][RDIM];

  const int t  = threadIdx.x;
  const int tg = t & 31;
  const int rc = t >> 5;
  const int row0 = tg * 2, row1 = tg * 2 + 1;
  const int rA = t >> 3, rB = rA + 32, jA = t & 7;
  const int tokA = (rA < nrows) ? (list_tk[base + rA] >> 3) : -1;
  const int tokB = (rB < nrows) ? (list_tk[base + rB] >> 3) : -1;

  float acc0[16], acc1[16];
#pragma unroll
  for (int j = 0; j < 16; ++j) { acc0[j] = 0.f; acc1[j] = 0.f; }
  const float* cbase = cn + (size_t)n * DDIM * RDIM;

  for (int dc = 0; dc < DDIM; dc += 32) {
    {
      float4 v = make_float4(0.f, 0.f, 0.f, 0.f);
      if (tokA >= 0) v = *reinterpret_cast<const float4*>(x + (size_t)tokA * DDIM + dc + jA * 4);
      xs[rA][jA * 4 + 0] = v.x; xs[rA][jA * 4 + 1] = v.y;
      xs[rA][jA * 4 + 2] = v.z; xs[rA][jA * 4 + 3] = v.w;
      float4 u = make_float4(0.f, 0.f, 0.f, 0.f);
      if (tokB >= 0) u = *reinterpret_cast<const float4*>(x + (size_t)tokB * DDIM + dc + jA * 4);
      xs[rB][jA * 4 + 0] = u.x; xs[rB][jA * 4 + 1] = u.y;
      xs[rB][jA * 4 + 2] = u.z; xs[rB][jA * 4 + 3] = u.w;
    }
#pragma unroll
    for (int p = 0; p < 4; ++p) {
      const int f = t + p * 256;
      const int dr = f >> 5, c4 = f & 31;
      float4 v = *reinterpret_cast<const float4*>(cbase + (size_t)(dc + dr) * RDIM + c4 * 4);
      *reinterpret_cast<float4*>(&cs[dr][c4 * 4]) = v;
    }
    __syncthreads();
#pragma unroll 4
    for (int d = 0; d < 32; ++d) {
      const float x0 = xs[row0][d];
      const float x1 = xs[row1][d];
      const float4* cp = reinterpret_cast<const float4*>(&cs[d][rc * 16]);
      float cv[16];
      *reinterpret_cast<float4*>(&cv[0])  = cp[0];
      *reinterpret_cast<float4*>(&cv[4])  = cp[1];
      *reinterpret_cast<float4*>(&cv[8])  = cp[2];
      *reinterpret_cast<float4*>(&cv[12]) = cp[3];
#pragma unroll
      for (int j = 0; j < 16; ++j) { acc0[j] += x0 * cv[j]; acc1[j] += x1 * cv[j]; }
    }
    __syncthreads();
  }
  if (row0 < nrows) {
    const int tk = list_tk[base + row0];
    const float wg = list_w[base + row0];
    float* orow = out + OUT_O_OFF + (size_t)(tk >> 3) * RDIM + rc * 16;
#pragma unroll
    for (int j = 0; j < 16; ++j) unsafeAtomicAdd(&orow[j], acc0[j] * wg);
  }
  if (row1 < nrows) {
    const int tk = list_tk[base + row1];
    const float wg = list_w[base + row1];
    float* orow = out + OUT_O_OFF + (size_t)(tk >> 3) * RDIM + rc * 16;
#pragma unroll
    for (int j = 0; j < 16; ++j) unsafeAtomicAdd(&orow[j], acc1[j] * wg);
  }
}

// ---------------------------------------------------------------------------
extern "C" void kernel_launch(void* const* d_in, const int* in_sizes, int n_in,
                              void* d_out, int out_size, void* d_ws, size_t ws_size,
                              hipStream_t stream)
{
  (void)in_sizes; (void)n_in; (void)out_size;

  const float* x  = (const float*)d_in[0];
  const float* rw = (const float*)d_in[1];
  const float* cn = (const float*)d_in[2];
  float* out = (float*)d_out;

  char* wsb = (char*)d_ws;
  int*   counts   = (int*)(wsb);
  int*   fill     = (int*)(wsb + 256);
  int*   offsets  = (int*)(wsb + 512);
  int*   list_tk  = (int*)(wsb + 1024);
  float* list_w   = (float*)(wsb + 1024 + (size_t)T_TOK * TOPK * sizeof(int));

  const size_t OFF_XBF  = 525312;
  const size_t SZ_XBF   = (size_t)T_TOK * DDIM * 2;
  const size_t SZ_CNBT  = (size_t)NEXP * RDIM * DDIM * 2;
  const size_t SZ_PROJ  = (size_t)T_TOK * TOPK * RDIM * 2;
  u16* xbf    = (u16*)(wsb + OFF_XBF);
  u16* cnbt   = (u16*)(wsb + OFF_XBF + SZ_XBF);
  u16* projbf = (u16*)(wsb + OFF_XBF + SZ_XBF + SZ_CNBT);

  const int tier = (ws_size >= OFF_XBF + SZ_XBF + SZ_CNBT + SZ_PROJ) ? 0
                 : (ws_size >= OFF_XBF + SZ_XBF + SZ_CNBT)           ? 1 : 2;

  hipMemsetAsync(wsb, 0, 1024, stream);
  if (tier != 0)
    hipMemsetAsync(d_out, 0, (size_t)T_TOK * RDIM * sizeof(float), stream);

  if (tier <= 1) {
    convert_x_kernel<<<4096, 256, 0, stream>>>(x, xbf);
    convert_cn_kernel<<<dim3(NEXP, 32, 4), 256, 0, stream>>>(cn, cnbt);
  }

  router_gemm_kernel<<<T_TOK / 32, 256, 0, stream>>>(x, rw, out);
  topk_kernel<<<T_TOK / 4, 256, 0, stream>>>(out, counts);
  scan_kernel<<<1, 64, 0, stream>>>(counts, offsets);
  scatter_kernel<<<T_TOK * TOPK / 256, 256, 0, stream>>>(out, offsets, fill, list_tk, list_w);

  dim3 grid(NEXP, 128);  // cnt <= 8192 per expert -> 128 tiles of 64 covers all
  if (tier == 0) {
    mfma_gemm_kernel<0><<<grid, 256, 0, stream>>>(xbf, cnbt, counts, offsets, list_tk, out, projbf);
    combine_kernel<<<T_TOK / 4, 256, 0, stream>>>(projbf, out);
  } else if (tier == 1) {
    mfma_gemm_kernel<1><<<grid, 256, 0, stream>>>(xbf, cnbt, counts, offsets, list_tk, out, projbf);
  } else {
    gemm_f32_kernel<<<grid, 256, 0, stream>>>(x, cn, counts, offsets, list_tk, list_w, out);
  }
}

// Round 3
// 219.494 us; speedup vs baseline: 5.3227x; 1.6548x over previous
//
#include <hip/hip_runtime.h>
#include <math.h>

typedef unsigned int  u32;
typedef unsigned short u16;
typedef unsigned long long u64;

// Problem constants (B=4, S=2048, D=1024, R=128, N=64, K=8)
#define T_TOK 8192
#define DDIM  1024
#define RDIM  128
#define NEXP  64
#define TOPK  8

// d_out layout (floats), reference return order: output, weights, topk_idx, scores
#define OUT_O_OFF 0
#define OUT_W_OFF (T_TOK * RDIM)                 // 1048576
#define OUT_I_OFF (OUT_W_OFF + T_TOK * TOPK)     // 1114112
#define OUT_S_OFF (OUT_I_OFF + T_TOK * TOPK)     // 1179648

// ws layout (bytes) — identical footprint to round 2
//   0        counts   int[64]
//   256      offsets  int[64]
//   1024     list_tk  int[65536]   (entry = token*8 + kpos, per-expert compacted)
//   263168   idx_int  int[65536]   (expert index per (token,k) slot)
//   525312   x_bf     u16[8192*1024]        (16 MB)
//   +16M     cn_bt    u16[64*128*1024]      (16 MB, [n][r][d])
//   +32M     proj_bf  u16[65536*128]        (16 MB, slot = token*8+k)

typedef __attribute__((ext_vector_type(8))) short bf16x8;
typedef __attribute__((ext_vector_type(4))) float f32x4;

__device__ __forceinline__ u16 f2bf(float f) {
  union { float f; u32 u; } v; v.f = f;
  u32 r = v.u + 0x7fffu + ((v.u >> 16) & 1u);   // RNE
  return (u16)(r >> 16);
}
__device__ __forceinline__ float bf2f(u16 h) {
  union { u32 u; float f; } v; v.u = ((u32)h) << 16;
  return v.f;
}

// ---------------------------------------------------------------------------
// convert x fp32 -> bf16 (8 elems/thread)
// ---------------------------------------------------------------------------
__global__ __launch_bounds__(256) void convert_x_kernel(
    const float* __restrict__ x, u16* __restrict__ xbf)
{
  const int i = blockIdx.x * 256 + threadIdx.x;   // 0 .. 1048575
  const float4 a = reinterpret_cast<const float4*>(x)[i * 2];
  const float4 b = reinterpret_cast<const float4*>(x)[i * 2 + 1];
  uint4 o;
  o.x = (u32)f2bf(a.x) | ((u32)f2bf(a.y) << 16);
  o.y = (u32)f2bf(a.z) | ((u32)f2bf(a.w) << 16);
  o.z = (u32)f2bf(b.x) | ((u32)f2bf(b.y) << 16);
  o.w = (u32)f2bf(b.z) | ((u32)f2bf(b.w) << 16);
  reinterpret_cast<uint4*>(xbf)[i] = o;
}

// ---------------------------------------------------------------------------
// transpose+convert cn [n][d][r] fp32 -> cn_bt [n][r][d] bf16, 32x32 tiles
// ---------------------------------------------------------------------------
__global__ __launch_bounds__(256) void convert_cn_kernel(
    const float* __restrict__ cn, u16* __restrict__ cnbt)
{
  const int n  = blockIdx.x;
  const int d0 = blockIdx.y * 32;
  const int r0 = blockIdx.z * 32;
  __shared__ float ts[32][33];
  const int t = threadIdx.x;
  {
    const int dr = t >> 3, rq = t & 7;
    float4 v = *reinterpret_cast<const float4*>(
        cn + ((size_t)n * DDIM + d0 + dr) * RDIM + r0 + rq * 4);
    ts[dr][rq * 4 + 0] = v.x; ts[dr][rq * 4 + 1] = v.y;
    ts[dr][rq * 4 + 2] = v.z; ts[dr][rq * 4 + 3] = v.w;
  }
  __syncthreads();
  {
    const int rr = t >> 3, dq = t & 7;
    ushort4 o;
    o.x = f2bf(ts[dq * 4 + 0][rr]);
    o.y = f2bf(ts[dq * 4 + 1][rr]);
    o.z = f2bf(ts[dq * 4 + 2][rr]);
    o.w = f2bf(ts[dq * 4 + 3][rr]);
    *reinterpret_cast<ushort4*>(
        cnbt + ((size_t)n * RDIM + r0 + rr) * DDIM + d0 + dq * 4) = o;
  }
}

// ---------------------------------------------------------------------------
// Router GEMM: scores = x @ rw^T, fp64 accumulate in ascending-d order.
// Block = 32 tokens x 64 experts; thread = 2 tokens x 4 experts.
// ---------------------------------------------------------------------------
__global__ __launch_bounds__(256) void router_gemm_kernel(
    const float* __restrict__ x, const float* __restrict__ rw,
    float* __restrict__ out)
{
  const int tok0 = blockIdx.x * 32;
  const int t  = threadIdx.x;
  const int ti = t & 15;
  const int ei = t >> 4;
  const int ti2 = ti * 2;
  const int e4  = ei * 4;

  __shared__ float xs[32][68];
  __shared__ float wsm[64][68];

  double acc[2][4];
#pragma unroll
  for (int a = 0; a < 2; ++a)
#pragma unroll
    for (int b = 0; b < 4; ++b) acc[a][b] = 0.0;

  for (int dc = 0; dc < DDIM; dc += 64) {
#pragma unroll
    for (int p = 0; p < 2; ++p) {
      const int idx = t + p * 256;
      const int row = idx >> 4, q = idx & 15;
      float4 v = *reinterpret_cast<const float4*>(
          x + (size_t)(tok0 + row) * DDIM + dc + q * 4);
      *reinterpret_cast<float4*>(&xs[row][q * 4]) = v;
    }
#pragma unroll
    for (int p = 0; p < 4; ++p) {
      const int idx = t + p * 256;
      const int row = idx >> 4, q = idx & 15;
      float4 v = *reinterpret_cast<const float4*>(
          rw + (size_t)row * DDIM + dc + q * 4);
      *reinterpret_cast<float4*>(&wsm[row][q * 4]) = v;
    }
    __syncthreads();

#pragma unroll 2
    for (int d4 = 0; d4 < 64; d4 += 4) {
      float4 xv0 = *reinterpret_cast<const float4*>(&xs[ti2][d4]);
      float4 xv1 = *reinterpret_cast<const float4*>(&xs[ti2 + 1][d4]);
      float4 wv0 = *reinterpret_cast<const float4*>(&wsm[e4 + 0][d4]);
      float4 wv1 = *reinterpret_cast<const float4*>(&wsm[e4 + 1][d4]);
      float4 wv2 = *reinterpret_cast<const float4*>(&wsm[e4 + 2][d4]);
      float4 wv3 = *reinterpret_cast<const float4*>(&wsm[e4 + 3][d4]);
      acc[0][0] += (double)xv0.x * (double)wv0.x; acc[0][0] += (double)xv0.y * (double)wv0.y;
      acc[0][0] += (double)xv0.z * (double)wv0.z; acc[0][0] += (double)xv0.w * (double)wv0.w;
      acc[0][1] += (double)xv0.x * (double)wv1.x; acc[0][1] += (double)xv0.y * (double)wv1.y;
      acc[0][1] += (double)xv0.z * (double)wv1.z; acc[0][1] += (double)xv0.w * (double)wv1.w;
      acc[0][2] += (double)xv0.x * (double)wv2.x; acc[0][2] += (double)xv0.y * (double)wv2.y;
      acc[0][2] += (double)xv0.z * (double)wv2.z; acc[0][2] += (double)xv0.w * (double)wv2.w;
      acc[0][3] += (double)xv0.x * (double)wv3.x; acc[0][3] += (double)xv0.y * (double)wv3.y;
      acc[0][3] += (double)xv0.z * (double)wv3.z; acc[0][3] += (double)xv0.w * (double)wv3.w;
      acc[1][0] += (double)xv1.x * (double)wv0.x; acc[1][0] += (double)xv1.y * (double)wv0.y;
      acc[1][0] += (double)xv1.z * (double)wv0.z; acc[1][0] += (double)xv1.w * (double)wv0.w;
      acc[1][1] += (double)xv1.x * (double)wv1.x; acc[1][1] += (double)xv1.y * (double)wv1.y;
      acc[1][1] += (double)xv1.z * (double)wv1.z; acc[1][1] += (double)xv1.w * (double)wv1.w;
      acc[1][2] += (double)xv1.x * (double)wv2.x; acc[1][2] += (double)xv1.y * (double)wv2.y;
      acc[1][2] += (double)xv1.z * (double)wv2.z; acc[1][2] += (double)xv1.w * (double)wv2.w;
      acc[1][3] += (double)xv1.x * (double)wv3.x; acc[1][3] += (double)xv1.y * (double)wv3.y;
      acc[1][3] += (double)xv1.z * (double)wv3.z; acc[1][3] += (double)xv1.w * (double)wv3.w;
    }
    __syncthreads();
  }

#pragma unroll
  for (int a = 0; a < 2; ++a) {
    float4 o;
    o.x = (float)acc[a][0]; o.y = (float)acc[a][1];
    o.z = (float)acc[a][2]; o.w = (float)acc[a][3];
    *reinterpret_cast<float4*>(
        out + OUT_S_OFF + (size_t)(tok0 + ti2 + a) * NEXP + e4) = o;
  }
}

// ---------------------------------------------------------------------------
// Top-8 + softmax. 4 tokens per 256-thread block (one wave each).
// NO atomics — also writes an int copy of the indices for the compactor.
// ---------------------------------------------------------------------------
__global__ __launch_bounds__(256) void topk_kernel(
    float* __restrict__ out, int* __restrict__ idx_int)
{
  const int token = blockIdx.x * 4 + (threadIdx.x >> 6);
  const int lane  = threadIdx.x & 63;

  const float v = out[OUT_S_OFF + (size_t)token * NEXP + lane];
  float cur = v;
  float topv[TOPK];
  int   topi[TOPK];
  for (int k = 0; k < TOPK; ++k) {
    float bv = cur;
    int   bi = lane;
#pragma unroll
    for (int off = 32; off >= 1; off >>= 1) {
      float ov = __shfl_xor(bv, off);
      int   oi = __shfl_xor(bi, off);
      if (ov > bv || (ov == bv && oi < bi)) { bv = ov; bi = oi; }
    }
    topv[k] = bv;
    topi[k] = bi;
    if (lane == bi) cur = -INFINITY;
  }
  const float m = topv[0];
  float wk[TOPK];
  float s = 0.f;
#pragma unroll
  for (int k = 0; k < TOPK; ++k) { wk[k] = expf(topv[k] - m); s += wk[k]; }
  const float inv = 1.f / s;

  if (lane < TOPK) {
    out[OUT_W_OFF + (size_t)token * TOPK + lane] = wk[lane] * inv;
    out[OUT_I_OFF + (size_t)token * TOPK + lane] = (float)topi[lane];
    idx_int[(size_t)token * TOPK + lane] = topi[lane];
  }
}

// ---------------------------------------------------------------------------
// Deterministic per-expert compaction, zero atomics.
// Block n (one wave): pass 1 counts entries with idx < n (= offset[n]);
// pass 2 writes entries with idx == n in stable ascending order + count.
// ---------------------------------------------------------------------------
#define NENT (T_TOK * TOPK)   // 65536

__global__ __launch_bounds__(64) void compact_kernel(
    const int* __restrict__ idx_int, int* __restrict__ counts,
    int* __restrict__ offsets, int* __restrict__ list_tk)
{
  const int n = blockIdx.x;
  const int l = threadIdx.x;

  // pass 1: offset[n] = #entries with expert < n
  int lt = 0;
  for (int c = 0; c < NENT; c += 64 * 8) {
    int v[8];
#pragma unroll
    for (int j = 0; j < 8; ++j) v[j] = idx_int[c + j * 64 + l];
#pragma unroll
    for (int j = 0; j < 8; ++j) lt += __popcll(__ballot(v[j] < n));
  }
  const int base = lt;   // uniform across wave

  // pass 2: stable compaction of entries with expert == n
  int eq_run = 0;
  for (int c = 0; c < NENT; c += 64 * 8) {
    int v[8];
#pragma unroll
    for (int j = 0; j < 8; ++j) v[j] = idx_int[c + j * 64 + l];
#pragma unroll
    for (int j = 0; j < 8; ++j) {
      const u64 b = __ballot(v[j] == n);
      if (v[j] == n) {
        const int r = (int)__popcll(b & ((1ull << l) - 1ull));
        list_tk[base + eq_run + r] = c + j * 64 + l;
      }
      eq_run += (int)__popcll(b);
    }
  }
  if (l == 0) { counts[n] = eq_run; offsets[n] = base; }
}

// ---------------------------------------------------------------------------
// MFMA expert GEMM (unchanged from round 2, minus list_w).
// ---------------------------------------------------------------------------
template<int MODE>
__global__ __launch_bounds__(256) void mfma_gemm_kernel(
    const u16* __restrict__ xbf, const u16* __restrict__ cnbt,
    const int* __restrict__ counts, const int* __restrict__ offsets,
    const int* __restrict__ list_tk,
    float* __restrict__ out, u16* __restrict__ projbf)
{
  const int n = blockIdx.x;
  const int cnt = counts[n];
  const int start = blockIdx.y * 64;
  if (start >= cnt) return;
  const int nrows = min(64, cnt - start);
  const int base = offsets[n] + start;

  __shared__ __align__(16) u16 xsArr[64 * 64];
  __shared__ __align__(16) u16 bsArr[128 * 64];

  const int t = threadIdx.x;
  const int l = t & 63;
  const int w = t >> 6;
  const int cl = l & 15;
  const int kq = l >> 4;          // 0..3
  const int arow = w * 16 + cl;   // A row this lane reads

  const int rowA = t >> 3;        // 0..31
  const int rowB = rowA + 32;
  const int pA   = t & 7;
  const int tokA = (rowA < nrows) ? (list_tk[base + rowA] >> 3) : -1;
  const int tokB = (rowB < nrows) ? (list_tk[base + rowB] >> 3) : -1;

  f32x4 acc[8];
#pragma unroll
  for (int f = 0; f < 8; ++f) acc[f] = (f32x4){0.f, 0.f, 0.f, 0.f};

  const u16* cnb = cnbt + (size_t)n * RDIM * DDIM;
  const uint4 z4 = make_uint4(0, 0, 0, 0);

  for (int dc = 0; dc < DDIM; dc += 64) {
    {
      uint4 v = z4;
      if (tokA >= 0)
        v = *reinterpret_cast<const uint4*>(xbf + (size_t)tokA * DDIM + dc + pA * 8);
      *reinterpret_cast<uint4*>(&xsArr[rowA * 64 + ((pA ^ (rowA & 7)) * 8)]) = v;
      uint4 u = z4;
      if (tokB >= 0)
        u = *reinterpret_cast<const uint4*>(xbf + (size_t)tokB * DDIM + dc + pA * 8);
      *reinterpret_cast<uint4*>(&xsArr[rowB * 64 + ((pA ^ (rowB & 7)) * 8)]) = u;
    }
#pragma unroll
    for (int p4 = 0; p4 < 4; ++p4) {
      const int r = rowA + p4 * 32;
      uint4 v = *reinterpret_cast<const uint4*>(cnb + (size_t)r * DDIM + dc + pA * 8);
      *reinterpret_cast<uint4*>(&bsArr[r * 64 + ((pA ^ (r & 7)) * 8)]) = v;
    }
    __syncthreads();

#pragma unroll
    for (int ks = 0; ks < 2; ++ks) {
      const int piece = ks * 4 + kq;
      bf16x8 a = *reinterpret_cast<const bf16x8*>(
          &xsArr[arow * 64 + ((piece ^ (arow & 7)) * 8)]);
#pragma unroll
      for (int f = 0; f < 8; ++f) {
        const int r = f * 16 + cl;
        bf16x8 b = *reinterpret_cast<const bf16x8*>(
            &bsArr[r * 64 + ((piece ^ (r & 7)) * 8)]);
        acc[f] = __builtin_amdgcn_mfma_f32_16x16x32_bf16(a, b, acc[f], 0, 0, 0);
      }
    }
    __syncthreads();
  }

  // epilogue: C/D layout row=(l>>4)*4+reg, col = f*16 + (l&15)
#pragma unroll
  for (int j = 0; j < 4; ++j) {
    const int row = w * 16 + kq * 4 + j;
    if (row < nrows) {
      const int tk = list_tk[base + row];
      if (MODE == 0) {
        u16* prow = projbf + (size_t)tk * RDIM + cl;
#pragma unroll
        for (int f = 0; f < 8; ++f) prow[f * 16] = f2bf(acc[f][j]);
      } else {
        const float wg = out[OUT_W_OFF + tk];
        float* orow = out + OUT_O_OFF + (size_t)(tk >> 3) * RDIM + cl;
#pragma unroll
        for (int f = 0; f < 8; ++f) unsafeAtomicAdd(&orow[f * 16], wg * acc[f][j]);
      }
    }
  }
}

// ---------------------------------------------------------------------------
// Combine: out[tok][r] = sum_k w[tok][k] * proj[tok*8+k][r].  Wave per token.
// ---------------------------------------------------------------------------
__global__ __launch_bounds__(256) void combine_kernel(
    const u16* __restrict__ projbf, float* __restrict__ out)
{
  const int token = blockIdx.x * 4 + (threadIdx.x >> 6);
  const int l = threadIdx.x & 63;
  float wts[TOPK];
#pragma unroll
  for (int k = 0; k < TOPK; ++k) wts[k] = out[OUT_W_OFF + (size_t)token * TOPK + k];
  float s0 = 0.f, s1 = 0.f;
#pragma unroll
  for (int k = 0; k < TOPK; ++k) {
    const u32 u = *reinterpret_cast<const u32*>(
        projbf + ((size_t)token * TOPK + k) * RDIM + l * 2);
    s0 += wts[k] * bf2f((u16)(u & 0xffff));
    s1 += wts[k] * bf2f((u16)(u >> 16));
  }
  float2 o; o.x = s0; o.y = s1;
  *reinterpret_cast<float2*>(out + OUT_O_OFF + (size_t)token * RDIM + l * 2) = o;
}

// ---------------------------------------------------------------------------
// Tier-2 fallback: fp32 gemm, weight read via tk.
// ---------------------------------------------------------------------------
__global__ __launch_bounds__(256) void gemm_f32_kernel(
    const float* __restrict__ x, const float* __restrict__ cn,
    const int* __restrict__ counts, const int* __restrict__ offsets,
    const int* __restrict__ list_tk, float* __restrict__ out)
{
  const int n = blockIdx.x;
  const int cnt = counts[n];
  const int start = blockIdx.y * 64;
  if (start >= cnt) return;
  const int nrows = min(64, cnt - start);
  const int base = offsets[n] + start;

  __shared__ float xs[64][33];
  __shared__ float cs[32][RDIM];

  const int t  = threadIdx.x;
  const int tg = t & 31;
  const int rc = t >> 5;
  const int row0 = tg * 2, row1 = tg * 2 + 1;
  const int rA = t >> 3, rB = rA + 32, jA = t & 7;
  const int tokA = (rA < nrows) ? (list_tk[base + rA] >> 3) : -1;
  const int tokB = (rB < nrows) ? (list_tk[base + rB] >> 3) : -1;

  float acc0[16], acc1[16];
#pragma unroll
  for (int j = 0; j < 16; ++j) { acc0[j] = 0.f; acc1[j] = 0.f; }
  const float* cbase = cn + (size_t)n * DDIM * RDIM;

  for (int dc = 0; dc < DDIM; dc += 32) {
    {
      float4 v = make_float4(0.f, 0.f, 0.f, 0.f);
      if (tokA >= 0) v = *reinterpret_cast<const float4*>(x + (size_t)tokA * DDIM + dc + jA * 4);
      xs[rA][jA * 4 + 0] = v.x; xs[rA][jA * 4 + 1] = v.y;
      xs[rA][jA * 4 + 2] = v.z; xs[rA][jA * 4 + 3] = v.w;
      float4 u = make_float4(0.f, 0.f, 0.f, 0.f);
      if (tokB >= 0) u = *reinterpret_cast<const float4*>(x + (size_t)tokB * DDIM + dc + jA * 4);
      xs[rB][jA * 4 + 0] = u.x; xs[rB][jA * 4 + 1] = u.y;
      xs[rB][jA * 4 + 2] = u.z; xs[rB][jA * 4 + 3] = u.w;
    }
#pragma unroll
    for (int p = 0; p < 4; ++p) {
      const int f = t + p * 256;
      const int dr = f >> 5, c4 = f & 31;
      float4 v = *reinterpret_cast<const float4*>(cbase + (size_t)(dc + dr) * RDIM + c4 * 4);
      *reinterpret_cast<float4*>(&cs[dr][c4 * 4]) = v;
    }
    __syncthreads();
#pragma unroll 4
    for (int d = 0; d < 32; ++d) {
      const float x0 = xs[row0][d];
      const float x1 = xs[row1][d];
      const float4* cp = reinterpret_cast<const float4*>(&cs[d][rc * 16]);
      float cv[16];
      *reinterpret_cast<float4*>(&cv[0])  = cp[0];
      *reinterpret_cast<float4*>(&cv[4])  = cp[1];
      *reinterpret_cast<float4*>(&cv[8])  = cp[2];
      *reinterpret_cast<float4*>(&cv[12]) = cp[3];
#pragma unroll
      for (int j = 0; j < 16; ++j) { acc0[j] += x0 * cv[j]; acc1[j] += x1 * cv[j]; }
    }
    __syncthreads();
  }
  if (row0 < nrows) {
    const int tk = list_tk[base + row0];
    const float wg = out[OUT_W_OFF + tk];
    float* orow = out + OUT_O_OFF + (size_t)(tk >> 3) * RDIM + rc * 16;
#pragma unroll
    for (int j = 0; j < 16; ++j) unsafeAtomicAdd(&orow[j], acc0[j] * wg);
  }
  if (row1 < nrows) {
    const int tk = list_tk[base + row1];
    const float wg = out[OUT_W_OFF + tk];
    float* orow = out + OUT_O_OFF + (size_t)(tk >> 3) * RDIM + rc * 16;
#pragma unroll
    for (int j = 0; j < 16; ++j) unsafeAtomicAdd(&orow[j], acc1[j] * wg);
  }
}

// ---------------------------------------------------------------------------
extern "C" void kernel_launch(void* const* d_in, const int* in_sizes, int n_in,
                              void* d_out, int out_size, void* d_ws, size_t ws_size,
                              hipStream_t stream)
{
  (void)in_sizes; (void)n_in; (void)out_size;

  const float* x  = (const float*)d_in[0];
  const float* rw = (const float*)d_in[1];
  const float* cn = (const float*)d_in[2];
  float* out = (float*)d_out;

  char* wsb = (char*)d_ws;
  int* counts  = (int*)(wsb);
  int* offsets = (int*)(wsb + 256);
  int* list_tk = (int*)(wsb + 1024);
  int* idx_int = (int*)(wsb + 1024 + (size_t)NENT * sizeof(int));

  const size_t OFF_XBF  = 525312;
  const size_t SZ_XBF   = (size_t)T_TOK * DDIM * 2;
  const size_t SZ_CNBT  = (size_t)NEXP * RDIM * DDIM * 2;
  const size_t SZ_PROJ  = (size_t)T_TOK * TOPK * RDIM * 2;
  u16* xbf    = (u16*)(wsb + OFF_XBF);
  u16* cnbt   = (u16*)(wsb + OFF_XBF + SZ_XBF);
  u16* projbf = (u16*)(wsb + OFF_XBF + SZ_XBF + SZ_CNBT);

  const int tier = (ws_size >= OFF_XBF + SZ_XBF + SZ_CNBT + SZ_PROJ) ? 0
                 : (ws_size >= OFF_XBF + SZ_XBF + SZ_CNBT)           ? 1 : 2;

  if (tier != 0)
    hipMemsetAsync(d_out, 0, (size_t)T_TOK * RDIM * sizeof(float), stream);

  if (tier <= 1) {
    convert_x_kernel<<<4096, 256, 0, stream>>>(x, xbf);
    convert_cn_kernel<<<dim3(NEXP, 32, 4), 256, 0, stream>>>(cn, cnbt);
  }

  router_gemm_kernel<<<T_TOK / 32, 256, 0, stream>>>(x, rw, out);
  topk_kernel<<<T_TOK / 4, 256, 0, stream>>>(out, idx_int);
  compact_kernel<<<NEXP, 64, 0, stream>>>(idx_int, counts, offsets, list_tk);

  dim3 grid(NEXP, 128);  // cnt <= 8192 per expert -> 128 tiles of 64 covers all
  if (tier == 0) {
    mfma_gemm_kernel<0><<<grid, 256, 0, stream>>>(xbf, cnbt, counts, offsets, list_tk, out, projbf);
    combine_kernel<<<T_TOK / 4, 256, 0, stream>>>(projbf, out);
  } else if (tier == 1) {
    mfma_gemm_kernel<1><<<grid, 256, 0, stream>>>(xbf, cnbt, counts, offsets, list_tk, out, projbf);
  } else {
    gemm_f32_kernel<<<grid, 256, 0, stream>>>(x, cn, counts, offsets, list_tk, out);
  }
}

// Round 5
// 172.615 us; speedup vs baseline: 6.7682x; 1.2716x over previous
//
#include <hip/hip_runtime.h>
#include <math.h>

typedef unsigned int  u32;
typedef unsigned short u16;
typedef unsigned long long u64;

// Problem constants (B=4, S=2048, D=1024, R=128, N=64, K=8)
#define T_TOK 8192
#define DDIM  1024
#define RDIM  128
#define NEXP  64
#define TOPK  8
#define NENT  (T_TOK * TOPK)   // 65536
#define NCHUNK 256             // chunks of 256 entries

// d_out layout (floats), reference return order: output, weights, topk_idx, scores
#define OUT_O_OFF 0
#define OUT_W_OFF (T_TOK * RDIM)                 // 1048576
#define OUT_I_OFF (OUT_W_OFF + T_TOK * TOPK)     // 1114112
#define OUT_S_OFF (OUT_I_OFF + T_TOK * TOPK)     // 1179648

// ws layout (bytes) — FIXED round-4 overlap: histT is 65536 B (not 64512),
// so chunk_off must start at 590848, ending exactly at OFF_XBF=656384.
//   0        counts    int[64]
//   256      offsets   int[64]
//   1024     list_tk   int[65536]
//   263168   idx_int   int[65536]
//   525312   histT     int[64*256]   [525312, 590848)
//   590848   chunk_off int[64*256]   [590848, 656384)
//   656384   x_bf      u16[8192*1024]      (16 MB)
//   +16M     cn_bt     u16[64*128*1024]    (16 MB, [n][r][d])
//   +32M     proj_bf   u16[65536*128]      (16 MB, slot = token*8+k)

typedef __attribute__((ext_vector_type(8))) short bf16x8;
typedef __attribute__((ext_vector_type(4))) float f32x4;

__device__ __forceinline__ u16 f2bf(float f) {
  union { float f; u32 u; } v; v.f = f;
  u32 r = v.u + 0x7fffu + ((v.u >> 16) & 1u);   // RNE
  return (u16)(r >> 16);
}
__device__ __forceinline__ float bf2f(u16 h) {
  union { u32 u; float f; } v; v.u = ((u32)h) << 16;
  return v.f;
}

// ---------------------------------------------------------------------------
// convert x fp32 -> bf16 (8 elems/thread)
// ---------------------------------------------------------------------------
__global__ __launch_bounds__(256) void convert_x_kernel(
    const float* __restrict__ x, u16* __restrict__ xbf)
{
  const int i = blockIdx.x * 256 + threadIdx.x;   // 0 .. 1048575
  const float4 a = reinterpret_cast<const float4*>(x)[i * 2];
  const float4 b = reinterpret_cast<const float4*>(x)[i * 2 + 1];
  uint4 o;
  o.x = (u32)f2bf(a.x) | ((u32)f2bf(a.y) << 16);
  o.y = (u32)f2bf(a.z) | ((u32)f2bf(a.w) << 16);
  o.z = (u32)f2bf(b.x) | ((u32)f2bf(b.y) << 16);
  o.w = (u32)f2bf(b.z) | ((u32)f2bf(b.w) << 16);
  reinterpret_cast<uint4*>(xbf)[i] = o;
}

// ---------------------------------------------------------------------------
// transpose+convert cn [n][d][r] fp32 -> cn_bt [n][r][d] bf16, 32x32 tiles
// ---------------------------------------------------------------------------
__global__ __launch_bounds__(256) void convert_cn_kernel(
    const float* __restrict__ cn, u16* __restrict__ cnbt)
{
  const int n  = blockIdx.x;
  const int d0 = blockIdx.y * 32;
  const int r0 = blockIdx.z * 32;
  __shared__ float ts[32][33];
  const int t = threadIdx.x;
  {
    const int dr = t >> 3, rq = t & 7;
    float4 v = *reinterpret_cast<const float4*>(
        cn + ((size_t)n * DDIM + d0 + dr) * RDIM + r0 + rq * 4);
    ts[dr][rq * 4 + 0] = v.x; ts[dr][rq * 4 + 1] = v.y;
    ts[dr][rq * 4 + 2] = v.z; ts[dr][rq * 4 + 3] = v.w;
  }
  __syncthreads();
  {
    const int rr = t >> 3, dq = t & 7;
    ushort4 o;
    o.x = f2bf(ts[dq * 4 + 0][rr]);
    o.y = f2bf(ts[dq * 4 + 1][rr]);
    o.z = f2bf(ts[dq * 4 + 2][rr]);
    o.w = f2bf(ts[dq * 4 + 3][rr]);
    *reinterpret_cast<ushort4*>(
        cnbt + ((size_t)n * RDIM + r0 + rr) * DDIM + d0 + dq * 4) = o;
  }
}

// ---------------------------------------------------------------------------
// Router GEMM: scores = x @ rw^T, fp64 accumulate in ascending-d order.
// Block = 32 tokens x 64 experts; thread = 2 tokens x 4 experts.
// ---------------------------------------------------------------------------
__global__ __launch_bounds__(256) void router_gemm_kernel(
    const float* __restrict__ x, const float* __restrict__ rw,
    float* __restrict__ out)
{
  const int tok0 = blockIdx.x * 32;
  const int t  = threadIdx.x;
  const int ti = t & 15;
  const int ei = t >> 4;
  const int ti2 = ti * 2;
  const int e4  = ei * 4;

  __shared__ float xs[32][68];
  __shared__ float wsm[64][68];

  double acc[2][4];
#pragma unroll
  for (int a = 0; a < 2; ++a)
#pragma unroll
    for (int b = 0; b < 4; ++b) acc[a][b] = 0.0;

  for (int dc = 0; dc < DDIM; dc += 64) {
#pragma unroll
    for (int p = 0; p < 2; ++p) {
      const int idx = t + p * 256;
      const int row = idx >> 4, q = idx & 15;
      float4 v = *reinterpret_cast<const float4*>(
          x + (size_t)(tok0 + row) * DDIM + dc + q * 4);
      *reinterpret_cast<float4*>(&xs[row][q * 4]) = v;
    }
#pragma unroll
    for (int p = 0; p < 4; ++p) {
      const int idx = t + p * 256;
      const int row = idx >> 4, q = idx & 15;
      float4 v = *reinterpret_cast<const float4*>(
          rw + (size_t)row * DDIM + dc + q * 4);
      *reinterpret_cast<float4*>(&wsm[row][q * 4]) = v;
    }
    __syncthreads();

#pragma unroll 2
    for (int d4 = 0; d4 < 64; d4 += 4) {
      float4 xv0 = *reinterpret_cast<const float4*>(&xs[ti2][d4]);
      float4 xv1 = *reinterpret_cast<const float4*>(&xs[ti2 + 1][d4]);
      float4 wv0 = *reinterpret_cast<const float4*>(&wsm[e4 + 0][d4]);
      float4 wv1 = *reinterpret_cast<const float4*>(&wsm[e4 + 1][d4]);
      float4 wv2 = *reinterpret_cast<const float4*>(&wsm[e4 + 2][d4]);
      float4 wv3 = *reinterpret_cast<const float4*>(&wsm[e4 + 3][d4]);
      acc[0][0] += (double)xv0.x * (double)wv0.x; acc[0][0] += (double)xv0.y * (double)wv0.y;
      acc[0][0] += (double)xv0.z * (double)wv0.z; acc[0][0] += (double)xv0.w * (double)wv0.w;
      acc[0][1] += (double)xv0.x * (double)wv1.x; acc[0][1] += (double)xv0.y * (double)wv1.y;
      acc[0][1] += (double)xv0.z * (double)wv1.z; acc[0][1] += (double)xv0.w * (double)wv1.w;
      acc[0][2] += (double)xv0.x * (double)wv2.x; acc[0][2] += (double)xv0.y * (double)wv2.y;
      acc[0][2] += (double)xv0.z * (double)wv2.z; acc[0][2] += (double)xv0.w * (double)wv2.w;
      acc[0][3] += (double)xv0.x * (double)wv3.x; acc[0][3] += (double)xv0.y * (double)wv3.y;
      acc[0][3] += (double)xv0.z * (double)wv3.z; acc[0][3] += (double)xv0.w * (double)wv3.w;
      acc[1][0] += (double)xv1.x * (double)wv0.x; acc[1][0] += (double)xv1.y * (double)wv0.y;
      acc[1][0] += (double)xv1.z * (double)wv0.z; acc[1][0] += (double)xv1.w * (double)wv0.w;
      acc[1][1] += (double)xv1.x * (double)wv1.x; acc[1][1] += (double)xv1.y * (double)wv1.y;
      acc[1][1] += (double)xv1.z * (double)wv1.z; acc[1][1] += (double)xv1.w * (double)wv1.w;
      acc[1][2] += (double)xv1.x * (double)wv2.x; acc[1][2] += (double)xv1.y * (double)wv2.y;
      acc[1][2] += (double)xv1.z * (double)wv2.z; acc[1][2] += (double)xv1.w * (double)wv2.w;
      acc[1][3] += (double)xv1.x * (double)wv3.x; acc[1][3] += (double)xv1.y * (double)wv3.y;
      acc[1][3] += (double)xv1.z * (double)wv3.z; acc[1][3] += (double)xv1.w * (double)wv3.w;
    }
    __syncthreads();
  }

#pragma unroll
  for (int a = 0; a < 2; ++a) {
    float4 o;
    o.x = (float)acc[a][0]; o.y = (float)acc[a][1];
    o.z = (float)acc[a][2]; o.w = (float)acc[a][3];
    *reinterpret_cast<float4*>(
        out + OUT_S_OFF + (size_t)(tok0 + ti2 + a) * NEXP + e4) = o;
  }
}

// ---------------------------------------------------------------------------
// Top-8 + softmax. 4 tokens per 256-thread block (one wave each). No atomics.
// ---------------------------------------------------------------------------
__global__ __launch_bounds__(256) void topk_kernel(
    float* __restrict__ out, int* __restrict__ idx_int)
{
  const int token = blockIdx.x * 4 + (threadIdx.x >> 6);
  const int lane  = threadIdx.x & 63;

  const float v = out[OUT_S_OFF + (size_t)token * NEXP + lane];
  float cur = v;
  float topv[TOPK];
  int   topi[TOPK];
  for (int k = 0; k < TOPK; ++k) {
    float bv = cur;
    int   bi = lane;
#pragma unroll
    for (int off = 32; off >= 1; off >>= 1) {
      float ov = __shfl_xor(bv, off);
      int   oi = __shfl_xor(bi, off);
      if (ov > bv || (ov == bv && oi < bi)) { bv = ov; bi = oi; }
    }
    topv[k] = bv;
    topi[k] = bi;
    if (lane == bi) cur = -INFINITY;
  }
  const float m = topv[0];
  float wk[TOPK];
  float s = 0.f;
#pragma unroll
  for (int k = 0; k < TOPK; ++k) { wk[k] = expf(topv[k] - m); s += wk[k]; }
  const float inv = 1.f / s;

  if (lane < TOPK) {
    out[OUT_W_OFF + (size_t)token * TOPK + lane] = wk[lane] * inv;
    out[OUT_I_OFF + (size_t)token * TOPK + lane] = (float)topi[lane];
    idx_int[(size_t)token * TOPK + lane] = topi[lane];
  }
}

// ---------------------------------------------------------------------------
// Compaction phase A: per-chunk expert histogram (ballot, no atomics).
// ---------------------------------------------------------------------------
__global__ __launch_bounds__(256) void hist_kernel(
    const int* __restrict__ idx_int, int* __restrict__ histT)
{
  const int chunk = blockIdx.x;
  const int t = threadIdx.x;
  const int w = t >> 6, l = t & 63;
  const int v = idx_int[chunk * 256 + t];

  __shared__ int wh[4][64];
  int cnt = 0;
#pragma unroll 8
  for (int s = 0; s < NEXP; ++s) {
    const u64 b = __ballot(v == s);
    if (l == s) cnt = (int)__popcll(b);
  }
  wh[w][l] = cnt;
  __syncthreads();
  if (t < NEXP)
    histT[t * NCHUNK + chunk] = wh[0][t] + wh[1][t] + wh[2][t] + wh[3][t];
}

// ---------------------------------------------------------------------------
// Compaction phase B: per-expert exclusive scan over chunks + running base.
// Single block, 256 threads (thread = chunk).
// ---------------------------------------------------------------------------
__global__ __launch_bounds__(256) void offsets_kernel(
    const int* __restrict__ histT, int* __restrict__ chunk_off,
    int* __restrict__ counts, int* __restrict__ offsets)
{
  const int t = threadIdx.x;
  const int w = t >> 6, l = t & 63;
  __shared__ int wsum[4];
  __shared__ int tot;

  int base = 0;
  for (int n = 0; n < NEXP; ++n) {
    const int h = histT[n * NCHUNK + t];
    int s = h;
#pragma unroll
    for (int off = 1; off < 64; off <<= 1) {
      const int o = __shfl_up(s, off);
      if (l >= off) s += o;
    }
    if (l == 63) wsum[w] = s;
    __syncthreads();
    int wpre = 0;
#pragma unroll
    for (int w2 = 0; w2 < 4; ++w2) if (w2 < w) wpre += wsum[w2];
    const int incl = s + wpre;
    chunk_off[n * NCHUNK + t] = base + incl - h;
    if (t == 255) tot = incl;
    __syncthreads();
    if (t == 0) { offsets[n] = base; counts[n] = tot; }
    base += tot;
    __syncthreads();
  }
}

// ---------------------------------------------------------------------------
// Compaction phase C: stable scatter via ballot rank + per-wave hist prefix.
// ---------------------------------------------------------------------------
__global__ __launch_bounds__(256) void scatter_kernel(
    const int* __restrict__ idx_int, const int* __restrict__ chunk_off,
    int* __restrict__ list_tk)
{
  const int chunk = blockIdx.x;
  const int t = threadIdx.x;
  const int w = t >> 6, l = t & 63;
  const int e = chunk * 256 + t;
  const int v = idx_int[e];

  __shared__ int wh[4][64];
  int myrank = 0, cnt = 0;
#pragma unroll 8
  for (int s = 0; s < NEXP; ++s) {
    const u64 b = __ballot(v == s);
    if (v == s) myrank = (int)__popcll(b & ((1ull << l) - 1ull));
    if (l == s) cnt = (int)__popcll(b);
  }
  wh[w][l] = cnt;
  __syncthreads();
  int pre = 0;
#pragma unroll
  for (int w2 = 0; w2 < 4; ++w2) if (w2 < w) pre += wh[w2][v];
  list_tk[chunk_off[v * NCHUNK + chunk] + pre + myrank] = e;
}

// ---------------------------------------------------------------------------
// MFMA expert GEMM (unchanged).
// ---------------------------------------------------------------------------
template<int MODE>
__global__ __launch_bounds__(256) void mfma_gemm_kernel(
    const u16* __restrict__ xbf, const u16* __restrict__ cnbt,
    const int* __restrict__ counts, const int* __restrict__ offsets,
    const int* __restrict__ list_tk,
    float* __restrict__ out, u16* __restrict__ projbf)
{
  const int n = blockIdx.x;
  const int cnt = counts[n];
  const int start = blockIdx.y * 64;
  if (start >= cnt) return;
  const int nrows = min(64, cnt - start);
  const int base = offsets[n] + start;

  __shared__ __align__(16) u16 xsArr[64 * 64];
  __shared__ __align__(16) u16 bsArr[128 * 64];

  const int t = threadIdx.x;
  const int l = t & 63;
  const int w = t >> 6;
  const int cl = l & 15;
  const int kq = l >> 4;          // 0..3
  const int arow = w * 16 + cl;   // A row this lane reads

  const int rowA = t >> 3;        // 0..31
  const int rowB = rowA + 32;
  const int pA   = t & 7;
  const int tokA = (rowA < nrows) ? (list_tk[base + rowA] >> 3) : -1;
  const int tokB = (rowB < nrows) ? (list_tk[base + rowB] >> 3) : -1;

  f32x4 acc[8];
#pragma unroll
  for (int f = 0; f < 8; ++f) acc[f] = (f32x4){0.f, 0.f, 0.f, 0.f};

  const u16* cnb = cnbt + (size_t)n * RDIM * DDIM;
  const uint4 z4 = make_uint4(0, 0, 0, 0);

  for (int dc = 0; dc < DDIM; dc += 64) {
    {
      uint4 v = z4;
      if (tokA >= 0)
        v = *reinterpret_cast<const uint4*>(xbf + (size_t)tokA * DDIM + dc + pA * 8);
      *reinterpret_cast<uint4*>(&xsArr[rowA * 64 + ((pA ^ (rowA & 7)) * 8)]) = v;
      uint4 u = z4;
      if (tokB >= 0)
        u = *reinterpret_cast<const uint4*>(xbf + (size_t)tokB * DDIM + dc + pA * 8);
      *reinterpret_cast<uint4*>(&xsArr[rowB * 64 + ((pA ^ (rowB & 7)) * 8)]) = u;
    }
#pragma unroll
    for (int p4 = 0; p4 < 4; ++p4) {
      const int r = rowA + p4 * 32;
      uint4 v = *reinterpret_cast<const uint4*>(cnb + (size_t)r * DDIM + dc + pA * 8);
      *reinterpret_cast<uint4*>(&bsArr[r * 64 + ((pA ^ (r & 7)) * 8)]) = v;
    }
    __syncthreads();

#pragma unroll
    for (int ks = 0; ks < 2; ++ks) {
      const int piece = ks * 4 + kq;
      bf16x8 a = *reinterpret_cast<const bf16x8*>(
          &xsArr[arow * 64 + ((piece ^ (arow & 7)) * 8)]);
#pragma unroll
      for (int f = 0; f < 8; ++f) {
        const int r = f * 16 + cl;
        bf16x8 b = *reinterpret_cast<const bf16x8*>(
            &bsArr[r * 64 + ((piece ^ (r & 7)) * 8)]);
        acc[f] = __builtin_amdgcn_mfma_f32_16x16x32_bf16(a, b, acc[f], 0, 0, 0);
      }
    }
    __syncthreads();
  }

  // epilogue: C/D layout row=(l>>4)*4+reg, col = f*16 + (l&15)
#pragma unroll
  for (int j = 0; j < 4; ++j) {
    const int row = w * 16 + kq * 4 + j;
    if (row < nrows) {
      const int tk = list_tk[base + row];
      if (MODE == 0) {
        u16* prow = projbf + (size_t)tk * RDIM + cl;
#pragma unroll
        for (int f = 0; f < 8; ++f) prow[f * 16] = f2bf(acc[f][j]);
      } else {
        const float wg = out[OUT_W_OFF + tk];
        float* orow = out + OUT_O_OFF + (size_t)(tk >> 3) * RDIM + cl;
#pragma unroll
        for (int f = 0; f < 8; ++f) unsafeAtomicAdd(&orow[f * 16], wg * acc[f][j]);
      }
    }
  }
}

// ---------------------------------------------------------------------------
// Combine: out[tok][r] = sum_k w[tok][k] * proj[tok*8+k][r].  Wave per token.
// ---------------------------------------------------------------------------
__global__ __launch_bounds__(256) void combine_kernel(
    const u16* __restrict__ projbf, float* __restrict__ out)
{
  const int token = blockIdx.x * 4 + (threadIdx.x >> 6);
  const int l = threadIdx.x & 63;
  float wts[TOPK];
#pragma unroll
  for (int k = 0; k < TOPK; ++k) wts[k] = out[OUT_W_OFF + (size_t)token * TOPK + k];
  float s0 = 0.f, s1 = 0.f;
#pragma unroll
  for (int k = 0; k < TOPK; ++k) {
    const u32 u = *reinterpret_cast<const u32*>(
        projbf + ((size_t)token * TOPK + k) * RDIM + l * 2);
    s0 += wts[k] * bf2f((u16)(u & 0xffff));
    s1 += wts[k] * bf2f((u16)(u >> 16));
  }
  float2 o; o.x = s0; o.y = s1;
  *reinterpret_cast<float2*>(out + OUT_O_OFF + (size_t)token * RDIM + l * 2) = o;
}

// ---------------------------------------------------------------------------
// Tier-2 fallback: fp32 gemm, weight read via tk.
// ---------------------------------------------------------------------------
__global__ __launch_bounds__(256) void gemm_f32_kernel(
    const float* __restrict__ x, const float* __restrict__ cn,
    const int* __restrict__ counts, const int* __restrict__ offsets,
    const int* __restrict__ list_tk, float* __restrict__ out)
{
  const int n = blockIdx.x;
  const int cnt = counts[n];
  const int start = blockIdx.y * 64;
  if (start >= cnt) return;
  const int nrows = min(64, cnt - start);
  const int base = offsets[n] + start;

  __shared__ float xs[64][33];
  __shared__ float cs[32][RDIM];

  const int t  = threadIdx.x;
  const int tg = t & 31;
  const int rc = t >> 5;
  const int row0 = tg * 2, row1 = tg * 2 + 1;
  const int rA = t >> 3, rB = rA + 32, jA = t & 7;
  const int tokA = (rA < nrows) ? (list_tk[base + rA] >> 3) : -1;
  const int tokB = (rB < nrows) ? (list_tk[base + rB] >> 3) : -1;

  float acc0[16], acc1[16];
#pragma unroll
  for (int j = 0; j < 16; ++j) { acc0[j] = 0.f; acc1[j] = 0.f; }
  const float* cbase = cn + (size_t)n * DDIM * RDIM;

  for (int dc = 0; dc < DDIM; dc += 32) {
    {
      float4 v = make_float4(0.f, 0.f, 0.f, 0.f);
      if (tokA >= 0) v = *reinterpret_cast<const float4*>(x + (size_t)tokA * DDIM + dc + jA * 4);
      xs[rA][jA * 4 + 0] = v.x; xs[rA][jA * 4 + 1] = v.y;
      xs[rA][jA * 4 + 2] = v.z; xs[rA][jA * 4 + 3] = v.w;
      float4 u = make_float4(0.f, 0.f, 0.f, 0.f);
      if (tokB >= 0) u = *reinterpret_cast<const float4*>(x + (size_t)tokB * DDIM + dc + jA * 4);
      xs[rB][jA * 4 + 0] = u.x; xs[rB][jA * 4 + 1] = u.y;
      xs[rB][jA * 4 + 2] = u.z; xs[rB][jA * 4 + 3] = u.w;
    }
#pragma unroll
    for (int p = 0; p < 4; ++p) {
      const int f = t + p * 256;
      const int dr = f >> 5, c4 = f & 31;
      float4 v = *reinterpret_cast<const float4*>(cbase + (size_t)(dc + dr) * RDIM + c4 * 4);
      *reinterpret_cast<float4*>(&cs[dr][c4 * 4]) = v;
    }
    __syncthreads();
#pragma unroll 4
    for (int d = 0; d < 32; ++d) {
      const float x0 = xs[row0][d];
      const float x1 = xs[row1][d];
      const float4* cp = reinterpret_cast<const float4*>(&cs[d][rc * 16]);
      float cv[16];
      *reinterpret_cast<float4*>(&cv[0])  = cp[0];
      *reinterpret_cast<float4*>(&cv[4])  = cp[1];
      *reinterpret_cast<float4*>(&cv[8])  = cp[2];
      *reinterpret_cast<float4*>(&cv[12]) = cp[3];
#pragma unroll
      for (int j = 0; j < 16; ++j) { acc0[j] += x0 * cv[j]; acc1[j] += x1 * cv[j]; }
    }
    __syncthreads();
  }
  if (row0 < nrows) {
    const int tk = list_tk[base + row0];
    const float wg = out[OUT_W_OFF + tk];
    float* orow = out + OUT_O_OFF + (size_t)(tk >> 3) * RDIM + rc * 16;
#pragma unroll
    for (int j = 0; j < 16; ++j) unsafeAtomicAdd(&orow[j], acc0[j] * wg);
  }
  if (row1 < nrows) {
    const int tk = list_tk[base + row1];
    const float wg = out[OUT_W_OFF + tk];
    float* orow = out + OUT_O_OFF + (size_t)(tk >> 3) * RDIM + rc * 16;
#pragma unroll
    for (int j = 0; j < 16; ++j) unsafeAtomicAdd(&orow[j], acc1[j] * wg);
  }
}

// ---------------------------------------------------------------------------
extern "C" void kernel_launch(void* const* d_in, const int* in_sizes, int n_in,
                              void* d_out, int out_size, void* d_ws, size_t ws_size,
                              hipStream_t stream)
{
  (void)in_sizes; (void)n_in; (void)out_size;

  const float* x  = (const float*)d_in[0];
  const float* rw = (const float*)d_in[1];
  const float* cn = (const float*)d_in[2];
  float* out = (float*)d_out;

  char* wsb = (char*)d_ws;
  int* counts    = (int*)(wsb);
  int* offsets   = (int*)(wsb + 256);
  int* list_tk   = (int*)(wsb + 1024);
  int* idx_int   = (int*)(wsb + 263168);
  int* histT     = (int*)(wsb + 525312);   // [525312, 590848)
  int* chunk_off = (int*)(wsb + 590848);   // [590848, 656384)  -- fixed overlap

  const size_t OFF_XBF  = 656384;
  const size_t SZ_XBF   = (size_t)T_TOK * DDIM * 2;
  const size_t SZ_CNBT  = (size_t)NEXP * RDIM * DDIM * 2;
  const size_t SZ_PROJ  = (size_t)T_TOK * TOPK * RDIM * 2;
  u16* xbf    = (u16*)(wsb + OFF_XBF);
  u16* cnbt   = (u16*)(wsb + OFF_XBF + SZ_XBF);
  u16* projbf = (u16*)(wsb + OFF_XBF + SZ_XBF + SZ_CNBT);

  const int tier = (ws_size >= OFF_XBF + SZ_XBF + SZ_CNBT + SZ_PROJ) ? 0
                 : (ws_size >= OFF_XBF + SZ_XBF + SZ_CNBT)           ? 1 : 2;

  if (tier != 0)
    hipMemsetAsync(d_out, 0, (size_t)T_TOK * RDIM * sizeof(float), stream);

  if (tier <= 1) {
    convert_x_kernel<<<4096, 256, 0, stream>>>(x, xbf);
    convert_cn_kernel<<<dim3(NEXP, 32, 4), 256, 0, stream>>>(cn, cnbt);
  }

  router_gemm_kernel<<<T_TOK / 32, 256, 0, stream>>>(x, rw, out);
  topk_kernel<<<T_TOK / 4, 256, 0, stream>>>(out, idx_int);

  hist_kernel<<<NCHUNK, 256, 0, stream>>>(idx_int, histT);
  offsets_kernel<<<1, 256, 0, stream>>>(histT, chunk_off, counts, offsets);
  scatter_kernel<<<NCHUNK, 256, 0, stream>>>(idx_int, chunk_off, list_tk);

  dim3 grid(NEXP, 128);  // cnt <= 8192 per expert -> 128 tiles of 64 covers all
  if (tier == 0) {
    mfma_gemm_kernel<0><<<grid, 256, 0, stream>>>(xbf, cnbt, counts, offsets, list_tk, out, projbf);
    combine_kernel<<<T_TOK / 4, 256, 0, stream>>>(projbf, out);
  } else if (tier == 1) {
    mfma_gemm_kernel<1><<<grid, 256, 0, stream>>>(xbf, cnbt, counts, offsets, list_tk, out, projbf);
  } else {
    gemm_f32_kernel<<<grid, 256, 0, stream>>>(x, cn, counts, offsets, list_tk, out);
  }
}

// Round 6
// 156.915 us; speedup vs baseline: 7.4454x; 1.1001x over previous
//
#include <hip/hip_runtime.h>
#include <math.h>

typedef unsigned int  u32;
typedef unsigned short u16;
typedef unsigned long long u64;

// Problem constants (B=4, S=2048, D=1024, R=128, N=64, K=8)
#define T_TOK 8192
#define DDIM  1024
#define RDIM  128
#define NEXP  64
#define TOPK  8
#define NENT  (T_TOK * TOPK)   // 65536
#define NCHUNK 256             // chunks of 256 entries
#define NSLICE 4               // router d-split

// d_out layout (floats), reference return order: output, weights, topk_idx, scores
#define OUT_O_OFF 0
#define OUT_W_OFF (T_TOK * RDIM)                 // 1048576
#define OUT_I_OFF (OUT_W_OFF + T_TOK * TOPK)     // 1114112
#define OUT_S_OFF (OUT_I_OFF + T_TOK * TOPK)     // 1179648

// ws layout (bytes)
//   0        counts    int[64]
//   256      offsets   int[64]
//   1024     list_tk   int[65536]
//   263168   idx_int   int[65536]
//   525312   histT     int[64*256]   [525312, 590848)
//   590848   chunk_off int[64*256]   [590848, 656384)
//   656384   x_bf      u16[8192*1024]      (16 MB)
//   +16M     cn_bt     u16[64*128*1024]    (16 MB, [n][r][d])
//   +32M     proj_bf   u16[65536*128]      (16 MB)
//   +48M     partials  double[4][8192][64] (16 MB)

typedef __attribute__((ext_vector_type(8))) short bf16x8;
typedef __attribute__((ext_vector_type(4))) float f32x4;

__device__ __forceinline__ u16 f2bf(float f) {
  union { float f; u32 u; } v; v.f = f;
  u32 r = v.u + 0x7fffu + ((v.u >> 16) & 1u);   // RNE
  return (u16)(r >> 16);
}
__device__ __forceinline__ float bf2f(u16 h) {
  union { u32 u; float f; } v; v.u = ((u32)h) << 16;
  return v.f;
}

// ---------------------------------------------------------------------------
// convert x fp32 -> bf16 (8 elems/thread)
// ---------------------------------------------------------------------------
__global__ __launch_bounds__(256) void convert_x_kernel(
    const float* __restrict__ x, u16* __restrict__ xbf)
{
  const int i = blockIdx.x * 256 + threadIdx.x;   // 0 .. 1048575
  const float4 a = reinterpret_cast<const float4*>(x)[i * 2];
  const float4 b = reinterpret_cast<const float4*>(x)[i * 2 + 1];
  uint4 o;
  o.x = (u32)f2bf(a.x) | ((u32)f2bf(a.y) << 16);
  o.y = (u32)f2bf(a.z) | ((u32)f2bf(a.w) << 16);
  o.z = (u32)f2bf(b.x) | ((u32)f2bf(b.y) << 16);
  o.w = (u32)f2bf(b.z) | ((u32)f2bf(b.w) << 16);
  reinterpret_cast<uint4*>(xbf)[i] = o;
}

// ---------------------------------------------------------------------------
// transpose+convert cn [n][d][r] fp32 -> cn_bt [n][r][d] bf16, 32x32 tiles
// ---------------------------------------------------------------------------
__global__ __launch_bounds__(256) void convert_cn_kernel(
    const float* __restrict__ cn, u16* __restrict__ cnbt)
{
  const int n  = blockIdx.x;
  const int d0 = blockIdx.y * 32;
  const int r0 = blockIdx.z * 32;
  __shared__ float ts[32][33];
  const int t = threadIdx.x;
  {
    const int dr = t >> 3, rq = t & 7;
    float4 v = *reinterpret_cast<const float4*>(
        cn + ((size_t)n * DDIM + d0 + dr) * RDIM + r0 + rq * 4);
    ts[dr][rq * 4 + 0] = v.x; ts[dr][rq * 4 + 1] = v.y;
    ts[dr][rq * 4 + 2] = v.z; ts[dr][rq * 4 + 3] = v.w;
  }
  __syncthreads();
  {
    const int rr = t >> 3, dq = t & 7;
    ushort4 o;
    o.x = f2bf(ts[dq * 4 + 0][rr]);
    o.y = f2bf(ts[dq * 4 + 1][rr]);
    o.z = f2bf(ts[dq * 4 + 2][rr]);
    o.w = f2bf(ts[dq * 4 + 3][rr]);
    *reinterpret_cast<ushort4*>(
        cnbt + ((size_t)n * RDIM + r0 + rr) * DDIM + d0 + dq * 4) = o;
  }
}

// ---------------------------------------------------------------------------
// Router GEMM body (macro-free): fp64 accumulate over [d0, d0+DLEN).
// Block = 32 tokens x 64 experts; thread = 2 tokens x 4 experts.
// ---------------------------------------------------------------------------
__device__ __forceinline__ void router_body(
    const float* __restrict__ x, const float* __restrict__ rw,
    int tok0, int d0, int dlen, double acc[2][4],
    float (*xs)[68], float (*wsm)[68])
{
  const int t  = threadIdx.x;
  const int ti2 = (t & 15) * 2;
  const int e4  = (t >> 4) * 4;

  for (int dc = d0; dc < d0 + dlen; dc += 64) {
#pragma unroll
    for (int p = 0; p < 2; ++p) {
      const int idx = t + p * 256;
      const int row = idx >> 4, q = idx & 15;
      float4 v = *reinterpret_cast<const float4*>(
          x + (size_t)(tok0 + row) * DDIM + dc + q * 4);
      *reinterpret_cast<float4*>(&xs[row][q * 4]) = v;
    }
#pragma unroll
    for (int p = 0; p < 4; ++p) {
      const int idx = t + p * 256;
      const int row = idx >> 4, q = idx & 15;
      float4 v = *reinterpret_cast<const float4*>(
          rw + (size_t)row * DDIM + dc + q * 4);
      *reinterpret_cast<float4*>(&wsm[row][q * 4]) = v;
    }
    __syncthreads();

#pragma unroll 2
    for (int d4 = 0; d4 < 64; d4 += 4) {
      float4 xv0 = *reinterpret_cast<const float4*>(&xs[ti2][d4]);
      float4 xv1 = *reinterpret_cast<const float4*>(&xs[ti2 + 1][d4]);
      float4 wv0 = *reinterpret_cast<const float4*>(&wsm[e4 + 0][d4]);
      float4 wv1 = *reinterpret_cast<const float4*>(&wsm[e4 + 1][d4]);
      float4 wv2 = *reinterpret_cast<const float4*>(&wsm[e4 + 2][d4]);
      float4 wv3 = *reinterpret_cast<const float4*>(&wsm[e4 + 3][d4]);
      acc[0][0] += (double)xv0.x * (double)wv0.x; acc[0][0] += (double)xv0.y * (double)wv0.y;
      acc[0][0] += (double)xv0.z * (double)wv0.z; acc[0][0] += (double)xv0.w * (double)wv0.w;
      acc[0][1] += (double)xv0.x * (double)wv1.x; acc[0][1] += (double)xv0.y * (double)wv1.y;
      acc[0][1] += (double)xv0.z * (double)wv1.z; acc[0][1] += (double)xv0.w * (double)wv1.w;
      acc[0][2] += (double)xv0.x * (double)wv2.x; acc[0][2] += (double)xv0.y * (double)wv2.y;
      acc[0][2] += (double)xv0.z * (double)wv2.z; acc[0][2] += (double)xv0.w * (double)wv2.w;
      acc[0][3] += (double)xv0.x * (double)wv3.x; acc[0][3] += (double)xv0.y * (double)wv3.y;
      acc[0][3] += (double)xv0.z * (double)wv3.z; acc[0][3] += (double)xv0.w * (double)wv3.w;
      acc[1][0] += (double)xv1.x * (double)wv0.x; acc[1][0] += (double)xv1.y * (double)wv0.y;
      acc[1][0] += (double)xv1.z * (double)wv0.z; acc[1][0] += (double)xv1.w * (double)wv0.w;
      acc[1][1] += (double)xv1.x * (double)wv1.x; acc[1][1] += (double)xv1.y * (double)wv1.y;
      acc[1][1] += (double)xv1.z * (double)wv1.z; acc[1][1] += (double)xv1.w * (double)wv1.w;
      acc[1][2] += (double)xv1.x * (double)wv2.x; acc[1][2] += (double)xv1.y * (double)wv2.y;
      acc[1][2] += (double)xv1.z * (double)wv2.z; acc[1][2] += (double)xv1.w * (double)wv2.w;
      acc[1][3] += (double)xv1.x * (double)wv3.x; acc[1][3] += (double)xv1.y * (double)wv3.y;
      acc[1][3] += (double)xv1.z * (double)wv3.z; acc[1][3] += (double)xv1.w * (double)wv3.w;
    }
    __syncthreads();
  }
}

// d-split partial router: grid (T_TOK/32, NSLICE); partials[slice][tok][exp]
__global__ __launch_bounds__(256) void router_part_kernel(
    const float* __restrict__ x, const float* __restrict__ rw,
    double* __restrict__ partials)
{
  __shared__ float xs[32][68];
  __shared__ float wsm[64][68];
  const int tok0 = blockIdx.x * 32;
  const int slice = blockIdx.y;
  double acc[2][4];
#pragma unroll
  for (int a = 0; a < 2; ++a)
#pragma unroll
    for (int b = 0; b < 4; ++b) acc[a][b] = 0.0;

  router_body(x, rw, tok0, slice * (DDIM / NSLICE), DDIM / NSLICE, acc, xs, wsm);

  const int ti2 = (threadIdx.x & 15) * 2;
  const int e4  = (threadIdx.x >> 4) * 4;
#pragma unroll
  for (int a = 0; a < 2; ++a) {
    double4 o;
    o.x = acc[a][0]; o.y = acc[a][1]; o.z = acc[a][2]; o.w = acc[a][3];
    *reinterpret_cast<double4*>(
        &partials[((size_t)slice * T_TOK + tok0 + ti2 + a) * NEXP + e4]) = o;
  }
}

// fallback single-pass router (round-5 proven): writes scores directly
__global__ __launch_bounds__(256) void router_gemm_kernel(
    const float* __restrict__ x, const float* __restrict__ rw,
    float* __restrict__ out)
{
  __shared__ float xs[32][68];
  __shared__ float wsm[64][68];
  const int tok0 = blockIdx.x * 32;
  double acc[2][4];
#pragma unroll
  for (int a = 0; a < 2; ++a)
#pragma unroll
    for (int b = 0; b < 4; ++b) acc[a][b] = 0.0;

  router_body(x, rw, tok0, 0, DDIM, acc, xs, wsm);

  const int ti2 = (threadIdx.x & 15) * 2;
  const int e4  = (threadIdx.x >> 4) * 4;
#pragma unroll
  for (int a = 0; a < 2; ++a) {
    float4 o;
    o.x = (float)acc[a][0]; o.y = (float)acc[a][1];
    o.z = (float)acc[a][2]; o.w = (float)acc[a][3];
    *reinterpret_cast<float4*>(
        out + OUT_S_OFF + (size_t)(tok0 + ti2 + a) * NEXP + e4) = o;
  }
}

// ---------------------------------------------------------------------------
// Top-8 + softmax. 4 tokens per 256-thread block (one wave each). No atomics.
// FOLD=1: first fold the 4 fp64 partials (ascending slice) -> score.
// ---------------------------------------------------------------------------
template<int FOLD>
__global__ __launch_bounds__(256) void topk_kernel(
    const double* __restrict__ partials,
    float* __restrict__ out, int* __restrict__ idx_int)
{
  const int token = blockIdx.x * 4 + (threadIdx.x >> 6);
  const int lane  = threadIdx.x & 63;

  float v;
  if (FOLD) {
    double s = 0.0;
#pragma unroll
    for (int sl = 0; sl < NSLICE; ++sl)
      s += partials[((size_t)sl * T_TOK + token) * NEXP + lane];
    v = (float)s;
    out[OUT_S_OFF + (size_t)token * NEXP + lane] = v;
  } else {
    v = out[OUT_S_OFF + (size_t)token * NEXP + lane];
  }

  float cur = v;
  float topv[TOPK];
  int   topi[TOPK];
  for (int k = 0; k < TOPK; ++k) {
    float bv = cur;
    int   bi = lane;
#pragma unroll
    for (int off = 32; off >= 1; off >>= 1) {
      float ov = __shfl_xor(bv, off);
      int   oi = __shfl_xor(bi, off);
      if (ov > bv || (ov == bv && oi < bi)) { bv = ov; bi = oi; }
    }
    topv[k] = bv;
    topi[k] = bi;
    if (lane == bi) cur = -INFINITY;
  }
  const float m = topv[0];
  float wk[TOPK];
  float s = 0.f;
#pragma unroll
  for (int k = 0; k < TOPK; ++k) { wk[k] = expf(topv[k] - m); s += wk[k]; }
  const float inv = 1.f / s;

  if (lane < TOPK) {
    out[OUT_W_OFF + (size_t)token * TOPK + lane] = wk[lane] * inv;
    out[OUT_I_OFF + (size_t)token * TOPK + lane] = (float)topi[lane];
    idx_int[(size_t)token * TOPK + lane] = topi[lane];
  }
}

// ---------------------------------------------------------------------------
// Compaction phase A: per-chunk expert histogram (ballot, no atomics).
// ---------------------------------------------------------------------------
__global__ __launch_bounds__(256) void hist_kernel(
    const int* __restrict__ idx_int, int* __restrict__ histT)
{
  const int chunk = blockIdx.x;
  const int t = threadIdx.x;
  const int w = t >> 6, l = t & 63;
  const int v = idx_int[chunk * 256 + t];

  __shared__ int wh[4][64];
  int cnt = 0;
#pragma unroll 8
  for (int s = 0; s < NEXP; ++s) {
    const u64 b = __ballot(v == s);
    if (l == s) cnt = (int)__popcll(b);
  }
  wh[w][l] = cnt;
  __syncthreads();
  if (t < NEXP)
    histT[t * NCHUNK + chunk] = wh[0][t] + wh[1][t] + wh[2][t] + wh[3][t];
}

// ---------------------------------------------------------------------------
// Compaction phase B: per-expert exclusive scan over chunks + running base.
// ---------------------------------------------------------------------------
__global__ __launch_bounds__(256) void offsets_kernel(
    const int* __restrict__ histT, int* __restrict__ chunk_off,
    int* __restrict__ counts, int* __restrict__ offsets)
{
  const int t = threadIdx.x;
  const int w = t >> 6, l = t & 63;
  __shared__ int wsum[4];
  __shared__ int tot;

  int base = 0;
  for (int n = 0; n < NEXP; ++n) {
    const int h = histT[n * NCHUNK + t];
    int s = h;
#pragma unroll
    for (int off = 1; off < 64; off <<= 1) {
      const int o = __shfl_up(s, off);
      if (l >= off) s += o;
    }
    if (l == 63) wsum[w] = s;
    __syncthreads();
    int wpre = 0;
#pragma unroll
    for (int w2 = 0; w2 < 4; ++w2) if (w2 < w) wpre += wsum[w2];
    const int incl = s + wpre;
    chunk_off[n * NCHUNK + t] = base + incl - h;
    if (t == 255) tot = incl;
    __syncthreads();
    if (t == 0) { offsets[n] = base; counts[n] = tot; }
    base += tot;
    __syncthreads();
  }
}

// ---------------------------------------------------------------------------
// Compaction phase C: stable scatter via ballot rank + per-wave hist prefix.
// ---------------------------------------------------------------------------
__global__ __launch_bounds__(256) void scatter_kernel(
    const int* __restrict__ idx_int, const int* __restrict__ chunk_off,
    int* __restrict__ list_tk)
{
  const int chunk = blockIdx.x;
  const int t = threadIdx.x;
  const int w = t >> 6, l = t & 63;
  const int e = chunk * 256 + t;
  const int v = idx_int[e];

  __shared__ int wh[4][64];
  int myrank = 0, cnt = 0;
#pragma unroll 8
  for (int s = 0; s < NEXP; ++s) {
    const u64 b = __ballot(v == s);
    if (v == s) myrank = (int)__popcll(b & ((1ull << l) - 1ull));
    if (l == s) cnt = (int)__popcll(b);
  }
  wh[w][l] = cnt;
  __syncthreads();
  int pre = 0;
#pragma unroll
  for (int w2 = 0; w2 < 4; ++w2) if (w2 < w) pre += wh[w2][v];
  list_tk[chunk_off[v * NCHUNK + chunk] + pre + myrank] = e;
}

// ---------------------------------------------------------------------------
// MFMA expert GEMM (unchanged).
// ---------------------------------------------------------------------------
template<int MODE>
__global__ __launch_bounds__(256) void mfma_gemm_kernel(
    const u16* __restrict__ xbf, const u16* __restrict__ cnbt,
    const int* __restrict__ counts, const int* __restrict__ offsets,
    const int* __restrict__ list_tk,
    float* __restrict__ out, u16* __restrict__ projbf)
{
  const int n = blockIdx.x;
  const int cnt = counts[n];
  const int start = blockIdx.y * 64;
  if (start >= cnt) return;
  const int nrows = min(64, cnt - start);
  const int base = offsets[n] + start;

  __shared__ __align__(16) u16 xsArr[64 * 64];
  __shared__ __align__(16) u16 bsArr[128 * 64];

  const int t = threadIdx.x;
  const int l = t & 63;
  const int w = t >> 6;
  const int cl = l & 15;
  const int kq = l >> 4;          // 0..3
  const int arow = w * 16 + cl;   // A row this lane reads

  const int rowA = t >> 3;        // 0..31
  const int rowB = rowA + 32;
  const int pA   = t & 7;
  const int tokA = (rowA < nrows) ? (list_tk[base + rowA] >> 3) : -1;
  const int tokB = (rowB < nrows) ? (list_tk[base + rowB] >> 3) : -1;

  f32x4 acc[8];
#pragma unroll
  for (int f = 0; f < 8; ++f) acc[f] = (f32x4){0.f, 0.f, 0.f, 0.f};

  const u16* cnb = cnbt + (size_t)n * RDIM * DDIM;
  const uint4 z4 = make_uint4(0, 0, 0, 0);

  for (int dc = 0; dc < DDIM; dc += 64) {
    {
      uint4 v = z4;
      if (tokA >= 0)
        v = *reinterpret_cast<const uint4*>(xbf + (size_t)tokA * DDIM + dc + pA * 8);
      *reinterpret_cast<uint4*>(&xsArr[rowA * 64 + ((pA ^ (rowA & 7)) * 8)]) = v;
      uint4 u = z4;
      if (tokB >= 0)
        u = *reinterpret_cast<const uint4*>(xbf + (size_t)tokB * DDIM + dc + pA * 8);
      *reinterpret_cast<uint4*>(&xsArr[rowB * 64 + ((pA ^ (rowB & 7)) * 8)]) = u;
    }
#pragma unroll
    for (int p4 = 0; p4 < 4; ++p4) {
      const int r = rowA + p4 * 32;
      uint4 v = *reinterpret_cast<const uint4*>(cnb + (size_t)r * DDIM + dc + pA * 8);
      *reinterpret_cast<uint4*>(&bsArr[r * 64 + ((pA ^ (r & 7)) * 8)]) = v;
    }
    __syncthreads();

#pragma unroll
    for (int ks = 0; ks < 2; ++ks) {
      const int piece = ks * 4 + kq;
      bf16x8 a = *reinterpret_cast<const bf16x8*>(
          &xsArr[arow * 64 + ((piece ^ (arow & 7)) * 8)]);
#pragma unroll
      for (int f = 0; f < 8; ++f) {
        const int r = f * 16 + cl;
        bf16x8 b = *reinterpret_cast<const bf16x8*>(
            &bsArr[r * 64 + ((piece ^ (r & 7)) * 8)]);
        acc[f] = __builtin_amdgcn_mfma_f32_16x16x32_bf16(a, b, acc[f], 0, 0, 0);
      }
    }
    __syncthreads();
  }

  // epilogue: C/D layout row=(l>>4)*4+reg, col = f*16 + (l&15)
#pragma unroll
  for (int j = 0; j < 4; ++j) {
    const int row = w * 16 + kq * 4 + j;
    if (row < nrows) {
      const int tk = list_tk[base + row];
      if (MODE == 0) {
        u16* prow = projbf + (size_t)tk * RDIM + cl;
#pragma unroll
        for (int f = 0; f < 8; ++f) prow[f * 16] = f2bf(acc[f][j]);
      } else {
        const float wg = out[OUT_W_OFF + tk];
        float* orow = out + OUT_O_OFF + (size_t)(tk >> 3) * RDIM + cl;
#pragma unroll
        for (int f = 0; f < 8; ++f) unsafeAtomicAdd(&orow[f * 16], wg * acc[f][j]);
      }
    }
  }
}

// ---------------------------------------------------------------------------
// Combine: out[tok][r] = sum_k w[tok][k] * proj[tok*8+k][r].  Wave per token.
// ---------------------------------------------------------------------------
__global__ __launch_bounds__(256) void combine_kernel(
    const u16* __restrict__ projbf, float* __restrict__ out)
{
  const int token = blockIdx.x * 4 + (threadIdx.x >> 6);
  const int l = threadIdx.x & 63;
  float wts[TOPK];
#pragma unroll
  for (int k = 0; k < TOPK; ++k) wts[k] = out[OUT_W_OFF + (size_t)token * TOPK + k];
  float s0 = 0.f, s1 = 0.f;
#pragma unroll
  for (int k = 0; k < TOPK; ++k) {
    const u32 u = *reinterpret_cast<const u32*>(
        projbf + ((size_t)token * TOPK + k) * RDIM + l * 2);
    s0 += wts[k] * bf2f((u16)(u & 0xffff));
    s1 += wts[k] * bf2f((u16)(u >> 16));
  }
  float2 o; o.x = s0; o.y = s1;
  *reinterpret_cast<float2*>(out + OUT_O_OFF + (size_t)token * RDIM + l * 2) = o;
}

// ---------------------------------------------------------------------------
// Tier-2 fallback: fp32 gemm, weight read via tk.
// ---------------------------------------------------------------------------
__global__ __launch_bounds__(256) void gemm_f32_kernel(
    const float* __restrict__ x, const float* __restrict__ cn,
    const int* __restrict__ counts, const int* __restrict__ offsets,
    const int* __restrict__ list_tk, float* __restrict__ out)
{
  const int n = blockIdx.x;
  const int cnt = counts[n];
  const int start = blockIdx.y * 64;
  if (start >= cnt) return;
  const int nrows = min(64, cnt - start);
  const int base = offsets[n] + start;

  __shared__ float xs[64][33];
  __shared__ float cs[32][RDIM];

  const int t  = threadIdx.x;
  const int tg = t & 31;
  const int rc = t >> 5;
  const int row0 = tg * 2, row1 = tg * 2 + 1;
  const int rA = t >> 3, rB = rA + 32, jA = t & 7;
  const int tokA = (rA < nrows) ? (list_tk[base + rA] >> 3) : -1;
  const int tokB = (rB < nrows) ? (list_tk[base + rB] >> 3) : -1;

  float acc0[16], acc1[16];
#pragma unroll
  for (int j = 0; j < 16; ++j) { acc0[j] = 0.f; acc1[j] = 0.f; }
  const float* cbase = cn + (size_t)n * DDIM * RDIM;

  for (int dc = 0; dc < DDIM; dc += 32) {
    {
      float4 v = make_float4(0.f, 0.f, 0.f, 0.f);
      if (tokA >= 0) v = *reinterpret_cast<const float4*>(x + (size_t)tokA * DDIM + dc + jA * 4);
      xs[rA][jA * 4 + 0] = v.x; xs[rA][jA * 4 + 1] = v.y;
      xs[rA][jA * 4 + 2] = v.z; xs[rA][jA * 4 + 3] = v.w;
      float4 u = make_float4(0.f, 0.f, 0.f, 0.f);
      if (tokB >= 0) u = *reinterpret_cast<const float4*>(x + (size_t)tokB * DDIM + dc + jA * 4);
      xs[rB][jA * 4 + 0] = u.x; xs[rB][jA * 4 + 1] = u.y;
      xs[rB][jA * 4 + 2] = u.z; xs[rB][jA * 4 + 3] = u.w;
    }
#pragma unroll
    for (int p = 0; p < 4; ++p) {
      const int f = t + p * 256;
      const int dr = f >> 5, c4 = f & 31;
      float4 v = *reinterpret_cast<const float4*>(cbase + (size_t)(dc + dr) * RDIM + c4 * 4);
      *reinterpret_cast<float4*>(&cs[dr][c4 * 4]) = v;
    }
    __syncthreads();
#pragma unroll 4
    for (int d = 0; d < 32; ++d) {
      const float x0 = xs[row0][d];
      const float x1 = xs[row1][d];
      const float4* cp = reinterpret_cast<const float4*>(&cs[d][rc * 16]);
      float cv[16];
      *reinterpret_cast<float4*>(&cv[0])  = cp[0];
      *reinterpret_cast<float4*>(&cv[4])  = cp[1];
      *reinterpret_cast<float4*>(&cv[8])  = cp[2];
      *reinterpret_cast<float4*>(&cv[12]) = cp[3];
#pragma unroll
      for (int j = 0; j < 16; ++j) { acc0[j] += x0 * cv[j]; acc1[j] += x1 * cv[j]; }
    }
    __syncthreads();
  }
  if (row0 < nrows) {
    const int tk = list_tk[base + row0];
    const float wg = out[OUT_W_OFF + tk];
    float* orow = out + OUT_O_OFF + (size_t)(tk >> 3) * RDIM + rc * 16;
#pragma unroll
    for (int j = 0; j < 16; ++j) unsafeAtomicAdd(&orow[j], acc0[j] * wg);
  }
  if (row1 < nrows) {
    const int tk = list_tk[base + row1];
    const float wg = out[OUT_W_OFF + tk];
    float* orow = out + OUT_O_OFF + (size_t)(tk >> 3) * RDIM + rc * 16;
#pragma unroll
    for (int j = 0; j < 16; ++j) unsafeAtomicAdd(&orow[j], acc1[j] * wg);
  }
}

// ---------------------------------------------------------------------------
extern "C" void kernel_launch(void* const* d_in, const int* in_sizes, int n_in,
                              void* d_out, int out_size, void* d_ws, size_t ws_size,
                              hipStream_t stream)
{
  (void)in_sizes; (void)n_in; (void)out_size;

  const float* x  = (const float*)d_in[0];
  const float* rw = (const float*)d_in[1];
  const float* cn = (const float*)d_in[2];
  float* out = (float*)d_out;

  char* wsb = (char*)d_ws;
  int* counts    = (int*)(wsb);
  int* offsets   = (int*)(wsb + 256);
  int* list_tk   = (int*)(wsb + 1024);
  int* idx_int   = (int*)(wsb + 263168);
  int* histT     = (int*)(wsb + 525312);   // [525312, 590848)
  int* chunk_off = (int*)(wsb + 590848);   // [590848, 656384)

  const size_t OFF_XBF  = 656384;
  const size_t SZ_XBF   = (size_t)T_TOK * DDIM * 2;
  const size_t SZ_CNBT  = (size_t)NEXP * RDIM * DDIM * 2;
  const size_t SZ_PROJ  = (size_t)T_TOK * TOPK * RDIM * 2;
  const size_t OFF_PART = OFF_XBF + SZ_XBF + SZ_CNBT + SZ_PROJ;
  const size_t SZ_PART  = (size_t)NSLICE * T_TOK * NEXP * sizeof(double);
  u16* xbf    = (u16*)(wsb + OFF_XBF);
  u16* cnbt   = (u16*)(wsb + OFF_XBF + SZ_XBF);
  u16* projbf = (u16*)(wsb + OFF_XBF + SZ_XBF + SZ_CNBT);
  double* partials = (double*)(wsb + OFF_PART);

  const int tier = (ws_size >= OFF_XBF + SZ_XBF + SZ_CNBT + SZ_PROJ) ? 0
                 : (ws_size >= OFF_XBF + SZ_XBF + SZ_CNBT)           ? 1 : 2;
  const bool splitR = (ws_size >= OFF_PART + SZ_PART);

  if (tier != 0)
    hipMemsetAsync(d_out, 0, (size_t)T_TOK * RDIM * sizeof(float), stream);

  if (tier <= 1) {
    convert_x_kernel<<<4096, 256, 0, stream>>>(x, xbf);
    convert_cn_kernel<<<dim3(NEXP, 32, 4), 256, 0, stream>>>(cn, cnbt);
  }

  if (splitR) {
    router_part_kernel<<<dim3(T_TOK / 32, NSLICE), 256, 0, stream>>>(x, rw, partials);
    topk_kernel<1><<<T_TOK / 4, 256, 0, stream>>>(partials, out, idx_int);
  } else {
    router_gemm_kernel<<<T_TOK / 32, 256, 0, stream>>>(x, rw, out);
    topk_kernel<0><<<T_TOK / 4, 256, 0, stream>>>(partials, out, idx_int);
  }

  hist_kernel<<<NCHUNK, 256, 0, stream>>>(idx_int, histT);
  offsets_kernel<<<1, 256, 0, stream>>>(histT, chunk_off, counts, offsets);
  scatter_kernel<<<NCHUNK, 256, 0, stream>>>(idx_int, chunk_off, list_tk);

  dim3 grid(NEXP, 128);  // cnt <= 8192 per expert -> 128 tiles of 64 covers all
  if (tier == 0) {
    mfma_gemm_kernel<0><<<grid, 256, 0, stream>>>(xbf, cnbt, counts, offsets, list_tk, out, projbf);
    combine_kernel<<<T_TOK / 4, 256, 0, stream>>>(projbf, out);
  } else if (tier == 1) {
    mfma_gemm_kernel<1><<<grid, 256, 0, stream>>>(xbf, cnbt, counts, offsets, list_tk, out, projbf);
  } else {
    gemm_f32_kernel<<<grid, 256, 0, stream>>>(x, cn, counts, offsets, list_tk, out);
  }
}